// Round 3
// baseline (14529.579 us; speedup 1.0000x reference)
//
#include <hip/hip_runtime.h>

using u16 = unsigned short;
typedef float f32x4 __attribute__((ext_vector_type(4)));
typedef short short8 __attribute__((ext_vector_type(8)));

// ---------- bf16 helpers (buffers held as u16; RNE conversion) ----------
__device__ __forceinline__ float bf2f(u16 u) {
  return __uint_as_float(((unsigned)u) << 16);
}
__device__ __forceinline__ u16 f2bf(float f) {
  unsigned u = __float_as_uint(f);
  unsigned r = u + 0x7fffu + ((u >> 16) & 1u);
  return (u16)(r >> 16);
}

// async global->LDS, 16B per lane; LDS dest is wave-uniform base + lane*16
__device__ __forceinline__ void gload16(const void* g, void* l) {
  __builtin_amdgcn_global_load_lds(
      reinterpret_cast<const __attribute__((address_space(1))) unsigned int*>(
          reinterpret_cast<uintptr_t>(g)),
      reinterpret_cast<__attribute__((address_space(3))) unsigned int*>(
          reinterpret_cast<uintptr_t>(l)),
      16, 0, 0);
}

// model constants
#define NBS 32
#define NSEQ 512
#define NNV 32
#define ND 512
#define NHID 1536
#define NPNUM 64
#define NPRED 96
#define MROWS 65536           // tokens per phase
#define RCHUNK 8192           // row chunk (multiple of 64)
#define NCHUNK (MROWS / RCHUNK)

// ---------------------------------------------------------------
// per-(b,v) mean / stdev over SEQ
// ---------------------------------------------------------------
__global__ __launch_bounds__(256) void stats_kernel(const float* __restrict__ tokens,
                                                    float* __restrict__ meanb,
                                                    float* __restrict__ invstd,
                                                    float* __restrict__ stdevb) {
  int bv = blockIdx.x;            // 0..1023
  int b = bv >> 5, v = bv & 31;
  int tid = threadIdx.x;
  float s = 0.f, s2 = 0.f;
  for (int t = tid; t < NSEQ; t += 256) {
    float x = tokens[((size_t)b * NSEQ + t) * NNV + v];
    s += x; s2 += x * x;
  }
  __shared__ float rs[256], rs2[256];
  rs[tid] = s; rs2[tid] = s2;
  __syncthreads();
  for (int o = 128; o; o >>= 1) {
    if (tid < o) { rs[tid] += rs[tid + o]; rs2[tid] += rs2[tid + o]; }
    __syncthreads();
  }
  if (tid == 0) {
    float m = rs[0] / (float)NSEQ;
    float var = rs2[0] / (float)NSEQ - m * m;
    float sd = sqrtf(var + 1e-5f);
    meanb[bv] = m;
    stdevb[bv] = sd;
    invstd[bv] = 1.f / sd;
  }
}

// ---------------------------------------------------------------
// weight convert + transpose: src f32 (K, N) -> dst bf16 rows (rowOff+n, k)
// grid (K/32, N/32), block 256
// ---------------------------------------------------------------
__global__ __launch_bounds__(256) void convt_kernel(const float* __restrict__ S,
                                                    u16* __restrict__ D,
                                                    int K, int N, int rowOff) {
  __shared__ float t[32][33];
  int k0 = blockIdx.x * 32, n0 = blockIdx.y * 32;
  int tx = threadIdx.x & 31, ty = threadIdx.x >> 5;    // ty 0..7
  for (int r = ty; r < 32; r += 8) t[r][tx] = S[(size_t)(k0 + r) * N + n0 + tx];
  __syncthreads();
  for (int r = ty; r < 32; r += 8) D[(size_t)(rowOff + n0 + r) * K + k0 + tx] = f2bf(t[tx][r]);
}

// ---------------------------------------------------------------
// patch embed: one block per (b,p); 32 output rows (v) of 512.
// ---------------------------------------------------------------
__global__ __launch_bounds__(256) void patch_embed(const float* __restrict__ tokens,
                                                   const float* __restrict__ pe_w,
                                                   const float* __restrict__ pe_b,
                                                   const float* __restrict__ meanb,
                                                   const float* __restrict__ invstd,
                                                   float* __restrict__ H) {
  __shared__ float pw[16 * ND];
  __shared__ float pv[32][16];
  int bp = blockIdx.x;                 // b*64+p
  int b = bp >> 6, p = bp & 63;
  int tid = threadIdx.x;
  for (int i = tid; i < 16 * ND; i += 256) pw[i] = pe_w[i];
  for (int idx = tid; idx < 512; idx += 256) {
    int v = idx >> 4, j = idx & 15;
    int t = p * 8 + j;
    if (t > NSEQ - 1) t = NSEQ - 1;    // repeat-last padding
    int bv = b * 32 + v;
    pv[v][j] = (tokens[((size_t)b * NSEQ + t) * NNV + v] - meanb[bv]) * invstd[bv];
  }
  __syncthreads();
  for (int o = tid; o < 32 * ND; o += 256) {
    int v = o >> 9, d = o & 511;
    float acc = pe_b[d];
#pragma unroll
    for (int j = 0; j < 16; j++) acc += pv[v][j] * pw[j * ND + d];
    H[((size_t)bp * 32 + v) * ND + d] = acc;
  }
}

// ---------------------------------------------------------------
// rmsnorm: fp32 rows (x 512) -> bf16 out, 1 wave per row
// ---------------------------------------------------------------
__global__ __launch_bounds__(256) void rmsnorm_bf16(const float* __restrict__ X,
                                                    const float* __restrict__ W,
                                                    u16* __restrict__ Y) {
  int wave = threadIdx.x >> 6, lane = threadIdx.x & 63;
  size_t row = (size_t)blockIdx.x * 4 + wave;
  const float4* xr = (const float4*)(X + row * ND);
  float4 a = xr[lane], b = xr[64 + lane];
  float s = a.x*a.x + a.y*a.y + a.z*a.z + a.w*a.w
          + b.x*b.x + b.y*b.y + b.z*b.z + b.w*b.w;
  for (int o = 1; o < 64; o <<= 1) s += __shfl_xor(s, o);
  float sc = rsqrtf(s * (1.f / ND) + 1e-5f);
  const float4* wr = (const float4*)W;
  float4 wa = wr[lane], wb = wr[64 + lane];
  ushort4 pa, pb;
  pa.x = f2bf(a.x * sc * wa.x); pa.y = f2bf(a.y * sc * wa.y);
  pa.z = f2bf(a.z * sc * wa.z); pa.w = f2bf(a.w * sc * wa.w);
  pb.x = f2bf(b.x * sc * wb.x); pb.y = f2bf(b.y * sc * wb.y);
  pb.z = f2bf(b.z * sc * wb.z); pb.w = f2bf(b.w * sc * wb.w);
  ushort4* yr = (ushort4*)(Y + row * ND);
  yr[lane] = pa; yr[64 + lane] = pb;
}

// rmsnorm + within-batch row permute (p,v)->(v,p), fp32 out to bounce.
// grid (512, GB); batch bb = blockIdx.y
__global__ __launch_bounds__(256) void rms_transpose_batch(const float* __restrict__ X,
                                                           const float* __restrict__ W,
                                                           float* __restrict__ Y) {
  int bb = blockIdx.y;
  X += (size_t)bb * 2048 * ND;
  Y += (size_t)bb * 2048 * ND;
  int wave = threadIdx.x >> 6, lane = threadIdx.x & 63;
  int row = blockIdx.x * 4 + wave;               // 0..2047 = p*32+v
  int p = row >> 5, v = row & 31;
  size_t r2 = (size_t)v * 64 + p;                // v*64+p
  const float4* xr = (const float4*)(X + (size_t)row * ND);
  float4 a = xr[lane], b4 = xr[64 + lane];
  float s = a.x*a.x + a.y*a.y + a.z*a.z + a.w*a.w
          + b4.x*b4.x + b4.y*b4.y + b4.z*b4.z + b4.w*b4.w;
  for (int o = 1; o < 64; o <<= 1) s += __shfl_xor(s, o);
  float sc = rsqrtf(s * (1.f / ND) + 1e-5f);
  const float4* wr = (const float4*)W;
  float4 wa = wr[lane], wb = wr[64 + lane];
  float4 oa, ob;
  oa.x = a.x * sc * wa.x;  oa.y = a.y * sc * wa.y;
  oa.z = a.z * sc * wa.z;  oa.w = a.w * sc * wa.w;
  ob.x = b4.x * sc * wb.x; ob.y = b4.y * sc * wb.y;
  ob.z = b4.z * sc * wb.z; ob.w = b4.w * sc * wb.w;
  float4* yr = (float4*)(Y + r2 * ND);
  yr[lane] = oa; yr[64 + lane] = ob;
}

__global__ __launch_bounds__(256) void copy_f32v4(const float4* __restrict__ S,
                                                  float4* __restrict__ D, int n) {
  int i = blockIdx.x * 256 + threadIdx.x;
  if (i < n) D[i] = S[i];
}

// ---------------------------------------------------------------
// MFMA GEMM: C[M,N] = A[M,K] @ Bt[N,K]^T ; A,Bt bf16(u16), acc fp32.
// MODE 0: store bf16 into Cb. MODE 1: Hres[M,N] += result (fp32).
// MODE 2: Cb[o] = silu(Cb[o]) * result (SwiGLU fusion; Cb in/out).
// block 256 = 4 waves (2x2 of 64x64), tile 128x128, BK=32.
// Staging via global_load_lds width=16 (m97 structure).
// grid (N/128, M/128)
// ---------------------------------------------------------------
template<int MODE>
__global__ __launch_bounds__(256) void gemm_bt(const u16* __restrict__ A,
                                               const u16* __restrict__ Bt,
                                               u16* __restrict__ Cb,
                                               float* __restrict__ Hres,
                                               int N, int K) {
  __shared__ u16 lA[128 * 32];
  __shared__ u16 lB[128 * 32];
  const int tid = threadIdx.x;
  const int lane = tid & 63;
  const int w = tid >> 6;
  const int wm = (w >> 1) * 64, wn = (w & 1) * 64;
  const int m0 = blockIdx.y * 128, n0 = blockIdx.x * 128;
  const int rowL = tid >> 2;            // 0..63
  const int colL = (tid & 3) * 8;       // k element offset within BK
  const int mfm = lane & 15, mfk = (lane >> 4) * 8;

  // per-lane global addresses; wave-uniform LDS bases (lane*16B is implicit)
  const u16* pA0 = A + (size_t)(m0 + rowL) * K + colL;
  const u16* pA1 = pA0 + (size_t)64 * K;
  const u16* pB0 = Bt + (size_t)(n0 + rowL) * K + colL;
  const u16* pB1 = pB0 + (size_t)64 * K;
  u16* dA0 = lA + w * 512;
  u16* dA1 = lA + 2048 + w * 512;
  u16* dB0 = lB + w * 512;
  u16* dB1 = lB + 2048 + w * 512;

  f32x4 acc[4][4] = {};

  for (int k0 = 0; k0 < K; k0 += 32) {
    __syncthreads();                    // prev iter's LDS reads done
    gload16(pA0 + k0, dA0);
    gload16(pA1 + k0, dA1);
    gload16(pB0 + k0, dB0);
    gload16(pB1 + k0, dB1);
    __syncthreads();                    // staging complete (vmcnt drained)
    short8 af[4], bfr[4];
#pragma unroll
    for (int i = 0; i < 4; i++) {
      af[i]  = *(const short8*)(lA + (wm + i * 16 + mfm) * 32 + mfk);
      bfr[i] = *(const short8*)(lB + (wn + i * 16 + mfm) * 32 + mfk);
    }
#pragma unroll
    for (int mi = 0; mi < 4; mi++)
#pragma unroll
      for (int ni = 0; ni < 4; ni++)
        acc[mi][ni] = __builtin_amdgcn_mfma_f32_16x16x32_bf16(af[mi], bfr[ni], acc[mi][ni], 0, 0, 0);
  }

  const int cr = (lane >> 4) * 4, cc = lane & 15;
#pragma unroll
  for (int mi = 0; mi < 4; mi++) {
#pragma unroll
    for (int ni = 0; ni < 4; ni++) {
#pragma unroll
      for (int i = 0; i < 4; i++) {
        int r = m0 + wm + mi * 16 + cr + i;
        int c = n0 + wn + ni * 16 + cc;
        size_t o = (size_t)r * N + c;
        if (MODE == 1) {
          Hres[o] += acc[mi][ni][i];
        } else if (MODE == 2) {
          float gf = bf2f(Cb[o]);
          Cb[o] = f2bf(gf / (1.f + __expf(-gf)) * acc[mi][ni][i]);
        } else {
          Cb[o] = f2bf(acc[mi][ni][i]);
        }
      }
    }
  }
}

// ---------------------------------------------------------------
// attention: one block per (head, group). QKV rows are 1536 wide
// [q|k|v], head slice 64. S=32 (rel) or S=64 (enc: rope + causal).
// ---------------------------------------------------------------
template<int S, bool ROPE>
__global__ __launch_bounds__(256) void attn_kernel(const u16* __restrict__ QKV,
                                                   u16* __restrict__ O) {
  __shared__ float qs[S][64];
  __shared__ float kbuf[S][65];       // padded rows; reused as v[S][64]
  __shared__ float ps[S][S];
  int h = blockIdx.x, bb = blockIdx.y, tid = threadIdx.x;
  size_t base = ((size_t)bb * S) * 1536 + h * 64;

  for (int idx = tid; idx < S * 64; idx += 256) {
    int s = idx >> 6, d = idx & 63;
    size_t o = base + (size_t)s * 1536 + d;
    qs[s][d] = bf2f(QKV[o]);
    kbuf[s][d] = bf2f(QKV[o + 512]);
  }
  __syncthreads();

  if (ROPE) {
    for (int idx = tid; idx < S * 32; idx += 256) {
      int s = idx >> 5, i = idx & 31;
      float inv = powf(10000.f, -(float)i * (1.f / 32.f));   // 10000^(-2i/64)
      float ang = (float)s * inv;
      float sn, cn;
      sincosf(ang, &sn, &cn);
      float xr = qs[s][2 * i], xi = qs[s][2 * i + 1];
      qs[s][2 * i] = xr * cn - xi * sn;
      qs[s][2 * i + 1] = xr * sn + xi * cn;
      xr = kbuf[s][2 * i]; xi = kbuf[s][2 * i + 1];
      kbuf[s][2 * i] = xr * cn - xi * sn;
      kbuf[s][2 * i + 1] = xr * sn + xi * cn;
    }
    __syncthreads();
  }

  constexpr int JG = S / 4;
  for (int idx = tid; idx < S * JG; idx += 256) {
    int i = idx / JG, j0 = (idx % JG) * 4;
    float a0 = 0, a1 = 0, a2 = 0, a3 = 0;
#pragma unroll 8
    for (int d = 0; d < 64; d++) {
      float q = qs[i][d];
      a0 += q * kbuf[j0 + 0][d];
      a1 += q * kbuf[j0 + 1][d];
      a2 += q * kbuf[j0 + 2][d];
      a3 += q * kbuf[j0 + 3][d];
    }
    const float sc = 0.125f;            // 1/sqrt(64)
    float4 r;
    if (ROPE) {
      r.x = (j0 + 0 <= i) ? a0 * sc : -1e30f;
      r.y = (j0 + 1 <= i) ? a1 * sc : -1e30f;
      r.z = (j0 + 2 <= i) ? a2 * sc : -1e30f;
      r.w = (j0 + 3 <= i) ? a3 * sc : -1e30f;
    } else {
      r.x = a0 * sc; r.y = a1 * sc; r.z = a2 * sc; r.w = a3 * sc;
    }
    *(float4*)&ps[i][j0] = r;
  }
  __syncthreads();

  // overwrite k's LDS with v (flat [S][64]); softmax runs concurrently on ps
  float* vs = &kbuf[0][0];
  for (int idx = tid; idx < S * 64; idx += 256) {
    int s = idx >> 6, d = idx & 63;
    vs[idx] = bf2f(QKV[base + (size_t)s * 1536 + 1024 + d]);
  }
  if (tid < S) {
    float m = -1e30f;
    for (int j = 0; j < S; j++) m = fmaxf(m, ps[tid][j]);
    float sum = 0.f;
    for (int j = 0; j < S; j++) {
      float e = __expf(ps[tid][j] - m);
      ps[tid][j] = e; sum += e;
    }
    float r = 1.f / sum;
    for (int j = 0; j < S; j++) ps[tid][j] *= r;
  }
  __syncthreads();

  for (int idx = tid; idx < S * 16; idx += 256) {
    int s = idx >> 4, d0 = (idx & 15) * 4;
    float a0 = 0, a1 = 0, a2 = 0, a3 = 0;
#pragma unroll 8
    for (int j = 0; j < S; j++) {
      float p = ps[s][j];
      const float* vr = vs + j * 64 + d0;
      a0 += p * vr[0]; a1 += p * vr[1]; a2 += p * vr[2]; a3 += p * vr[3];
    }
    size_t oo = ((size_t)bb * S + s) * 512 + h * 64 + d0;
    ushort4 pk;
    pk.x = f2bf(a0); pk.y = f2bf(a1); pk.z = f2bf(a2); pk.w = f2bf(a3);
    *(ushort4*)(O + oo) = pk;
  }
}

__global__ __launch_bounds__(256) void zero_f32(float* __restrict__ p, int n) {
  int i = blockIdx.x * 256 + threadIdx.x;
  if (i < n) p[i] = 0.f;
}

// ---------------------------------------------------------------
// head GEMM (per row-chunk): Z[128,96] += A[128,32768] @ Bt[96,32768]^T
// grid (2 m-tiles of 64, 32 k-chunks of 1024), block 256 = 4 waves
// ---------------------------------------------------------------
__global__ __launch_bounds__(256) void head_gemm(const u16* __restrict__ A,
                                                 const u16* __restrict__ Bt,
                                                 float* __restrict__ Z) {
  __shared__ u16 lA[64 * 32];
  __shared__ u16 lB[96 * 32];
  int tid = threadIdx.x, lane = tid & 63, w = tid >> 6;
  int m0 = blockIdx.x * 64;
  int kbase = blockIdx.y * 1024;
  const int mfm = lane & 15, mfk = (lane >> 4) * 8;
  f32x4 acc[6] = {};

  for (int kk = 0; kk < 1024; kk += 32) {
    int k0 = kbase + kk;
    uint4 a0 = *(const uint4*)(A + (size_t)(m0 + (tid >> 2)) * 32768 + k0 + (tid & 3) * 8);
    uint4 b0 = *(const uint4*)(Bt + (size_t)(tid >> 2) * 32768 + k0 + (tid & 3) * 8);
    uint4 b1;
    bool has2 = tid < 128;
    int slot2 = 256 + tid, row2 = slot2 >> 2, c82 = (slot2 & 3) * 8;
    if (has2) b1 = *(const uint4*)(Bt + (size_t)row2 * 32768 + k0 + c82);
    __syncthreads();
    *(uint4*)(lA + (tid >> 2) * 32 + (tid & 3) * 8) = a0;
    *(uint4*)(lB + (tid >> 2) * 32 + (tid & 3) * 8) = b0;
    if (has2) *(uint4*)(lB + row2 * 32 + c82) = b1;
    __syncthreads();
    short8 af = *(const short8*)(lA + (w * 16 + mfm) * 32 + mfk);
#pragma unroll
    for (int nt = 0; nt < 6; nt++) {
      short8 bfr = *(const short8*)(lB + (nt * 16 + mfm) * 32 + mfk);
      acc[nt] = __builtin_amdgcn_mfma_f32_16x16x32_bf16(af, bfr, acc[nt], 0, 0, 0);
    }
  }
  int cr = (lane >> 4) * 4, cc = lane & 15;
#pragma unroll
  for (int nt = 0; nt < 6; nt++)
#pragma unroll
    for (int i = 0; i < 4; i++)
      atomicAdd(&Z[(size_t)(m0 + w * 16 + cr + i) * NPRED + nt * 16 + cc], acc[nt][i]);
}

// out[b,t,v] = (Z[b*32+v, t] + head_b[t]) * stdev[b,v] + mean[b,v]
__global__ __launch_bounds__(256) void final_kernel(const float* __restrict__ Z,
                                                    const float* __restrict__ head_b,
                                                    const float* __restrict__ meanb,
                                                    const float* __restrict__ stdevb,
                                                    float* __restrict__ out) {
  int idx = blockIdx.x * 256 + threadIdx.x;
  if (idx >= NBS * NPRED * NNV) return;
  int v = idx & 31;
  int t = (idx >> 5) % NPRED;
  int b = idx / (NPRED * NNV);
  int bv = b * 32 + v;
  out[idx] = (Z[(size_t)bv * NPRED + t] + head_b[t]) * stdevb[bv] + meanb[bv];
}

// ---------------------------------------------------------------
extern "C" void kernel_launch(void* const* d_in, const int* in_sizes, int n_in,
                              void* d_out, int out_size, void* d_ws, size_t ws_size,
                              hipStream_t stream) {
  const float* tokens = (const float*)d_in[0];
  const float* pe_w   = (const float*)d_in[1];
  const float* pe_b   = (const float*)d_in[2];
  const float* norm_w = (const float*)d_in[3];
  const float* head_w = (const float*)d_in[4];
  const float* head_b = (const float*)d_in[5];
  const float* wq[2] = {(const float*)d_in[6],  (const float*)d_in[15]};
  const float* wk[2] = {(const float*)d_in[7],  (const float*)d_in[16]};
  const float* wv[2] = {(const float*)d_in[8],  (const float*)d_in[17]};
  const float* wo[2] = {(const float*)d_in[9],  (const float*)d_in[18]};
  const float* w1[2] = {(const float*)d_in[10], (const float*)d_in[19]};
  const float* w2[2] = {(const float*)d_in[11], (const float*)d_in[20]};
  const float* w3[2] = {(const float*)d_in[12], (const float*)d_in[21]};
  const float* an[2] = {(const float*)d_in[13], (const float*)d_in[22]};
  const float* fn[2] = {(const float*)d_in[14], (const float*)d_in[23]};

  char* ws = (char*)d_ws;
  size_t off = 0;
  auto alloc = [&](size_t bytes) -> void* {
    void* p = ws + off;
    off += (bytes + 255) & ~(size_t)255;
    return p;
  };
  // ~207 MB total workspace
  float* meanb  = (float*)alloc(1024 * 4);
  float* invstd = (float*)alloc(1024 * 4);
  float* stdevb = (float*)alloc(1024 * 4);
  u16* wl_qkv = (u16*)alloc((size_t)1536 * 512 * 2);    // current layer only
  u16* wl_o   = (u16*)alloc((size_t)512 * 512 * 2);
  u16* wl_1   = (u16*)alloc((size_t)1536 * 512 * 2);
  u16* wl_3   = (u16*)alloc((size_t)1536 * 512 * 2);
  u16* wl_2   = (u16*)alloc((size_t)512 * 1536 * 2);
  u16* hw_t   = (u16*)alloc((size_t)96 * 32768 * 2);
  float* z    = (float*)alloc((size_t)1024 * 96 * 4);
  float* h    = (float*)alloc((size_t)MROWS * ND * 4);          // 134 MB residual
  u16* xn     = (u16*)alloc((size_t)RCHUNK * ND * 2);           // 8.4 MB
  u16* g1     = (u16*)alloc((size_t)RCHUNK * NHID * 2);         // 25 MB
  u16* g2     = (u16*)alloc((size_t)RCHUNK * NHID * 2);         // 25 MB
  float* bounce = (float*)g1;   // 8*2048*512*4 = 33.5 MB, overlays dead g1+g2

  stats_kernel<<<1024, 256, 0, stream>>>(tokens, meanb, invstd, stdevb);
  convt_kernel<<<dim3(1024, 3), 256, 0, stream>>>(head_w, hw_t, 32768, 96, 0);
  patch_embed<<<2048, 256, 0, stream>>>(tokens, pe_w, pe_b, meanb, invstd, h);

  for (int l = 0; l < 8; l++) {
    int ph = l >> 2, li = l & 3;
    // convert this layer's weights to bf16 transposed (N x K)
    convt_kernel<<<dim3(16, 16), 256, 0, stream>>>(wq[ph] + (size_t)li * 512 * 512, wl_qkv, 512, 512, 0);
    convt_kernel<<<dim3(16, 16), 256, 0, stream>>>(wk[ph] + (size_t)li * 512 * 512, wl_qkv, 512, 512, 512);
    convt_kernel<<<dim3(16, 16), 256, 0, stream>>>(wv[ph] + (size_t)li * 512 * 512, wl_qkv, 512, 512, 1024);
    convt_kernel<<<dim3(16, 16), 256, 0, stream>>>(wo[ph] + (size_t)li * 512 * 512, wl_o, 512, 512, 0);
    convt_kernel<<<dim3(16, 48), 256, 0, stream>>>(w1[ph] + (size_t)li * 512 * 1536, wl_1, 512, 1536, 0);
    convt_kernel<<<dim3(16, 48), 256, 0, stream>>>(w3[ph] + (size_t)li * 512 * 1536, wl_3, 512, 1536, 0);
    convt_kernel<<<dim3(48, 16), 256, 0, stream>>>(w2[ph] + (size_t)li * 1536 * 512, wl_2, 1536, 512, 0);
    const float* anl = an[ph] + li * 512;
    const float* fnl = fn[ph] + li * 512;

    for (int c = 0; c < NCHUNK; c++) {
      float* hc = h + (size_t)c * RCHUNK * ND;
      rmsnorm_bf16<<<RCHUNK / 4, 256, 0, stream>>>(hc, anl, xn);
      gemm_bt<0><<<dim3(12, RCHUNK / 128), 256, 0, stream>>>(xn, wl_qkv, g1, (float*)nullptr, 1536, 512);
      if (ph == 0) attn_kernel<32, false><<<dim3(8, RCHUNK / 32), 256, 0, stream>>>(g1, g2);
      else         attn_kernel<64, true ><<<dim3(8, RCHUNK / 64), 256, 0, stream>>>(g1, g2);
      gemm_bt<1><<<dim3(4, RCHUNK / 128), 256, 0, stream>>>(g2, wl_o, (u16*)nullptr, hc, 512, 512);
      rmsnorm_bf16<<<RCHUNK / 4, 256, 0, stream>>>(hc, fnl, xn);
      gemm_bt<0><<<dim3(12, RCHUNK / 128), 256, 0, stream>>>(xn, wl_1, g1, (float*)nullptr, 1536, 512);
      // W3 with fused SwiGLU epilogue: g1 = silu(g1) * (xn @ W3)
      gemm_bt<2><<<dim3(12, RCHUNK / 128), 256, 0, stream>>>(xn, wl_3, g1, (float*)nullptr, 1536, 512);
      gemm_bt<1><<<dim3(4, RCHUNK / 128), 256, 0, stream>>>(g1, wl_2, (u16*)nullptr, hc, 512, 1536);
    }

    if (l == 3) {
      // rel->enc handoff: rms_norm + within-batch (p,v)->(v,p) row permute,
      // 8 batches per round through the 33.5 MB bounce (g1/g2 space is dead)
      for (int g = 0; g < 4; g++) {
        float* hg = h + (size_t)g * 8 * 2048 * ND;
        rms_transpose_batch<<<dim3(512, 8), 256, 0, stream>>>(hg, norm_w, bounce);
        copy_f32v4<<<8192, 256, 0, stream>>>((const float4*)bounce, (float4*)hg, 8 * 2048 * ND / 4);
      }
    }
  }

  // head: per-chunk rmsnorm -> 128 complete M-rows of the 1024x96x32768 GEMM
  zero_f32<<<384, 256, 0, stream>>>(z, 1024 * 96);
  for (int c = 0; c < NCHUNK; c++) {
    rmsnorm_bf16<<<RCHUNK / 4, 256, 0, stream>>>(h + (size_t)c * RCHUNK * ND, norm_w, xn);
    head_gemm<<<dim3(2, 32), 256, 0, stream>>>(xn, hw_t, z + (size_t)c * 128 * NPRED);
  }
  final_kernel<<<384, 256, 0, stream>>>(z, head_b, meanb, stdevb, (float*)d_out);
}

// Round 4
// 10438.647 us; speedup vs baseline: 1.3919x; 1.3919x over previous
//
#include <hip/hip_runtime.h>

using u16 = unsigned short;
typedef float f32x4 __attribute__((ext_vector_type(4)));
typedef short short8 __attribute__((ext_vector_type(8)));

// ---------- bf16 helpers (buffers held as u16; RNE conversion) ----------
__device__ __forceinline__ float bf2f(u16 u) {
  return __uint_as_float(((unsigned)u) << 16);
}
__device__ __forceinline__ u16 f2bf(float f) {
  unsigned u = __float_as_uint(f);
  unsigned r = u + 0x7fffu + ((u >> 16) & 1u);
  return (u16)(r >> 16);
}

// async global->LDS, 16B per lane; LDS dest is wave-uniform base + lane*16
__device__ __forceinline__ void gload16(const void* g, void* l) {
  __builtin_amdgcn_global_load_lds(
      reinterpret_cast<const __attribute__((address_space(1))) unsigned int*>(
          reinterpret_cast<uintptr_t>(g)),
      reinterpret_cast<__attribute__((address_space(3))) unsigned int*>(
          reinterpret_cast<uintptr_t>(l)),
      16, 0, 0);
}

// model constants
#define NBS 32
#define NSEQ 512
#define NNV 32
#define ND 512
#define NHID 1536
#define NPNUM 64
#define NPRED 96
#define MROWS 65536           // tokens per phase
#define RCHUNK 16384          // row chunk (multiple of 64)
#define NCHUNK (MROWS / RCHUNK)

// ---------------------------------------------------------------
// per-(b,v) mean / stdev over SEQ
// ---------------------------------------------------------------
__global__ __launch_bounds__(256) void stats_kernel(const float* __restrict__ tokens,
                                                    float* __restrict__ meanb,
                                                    float* __restrict__ invstd,
                                                    float* __restrict__ stdevb) {
  int bv = blockIdx.x;            // 0..1023
  int b = bv >> 5, v = bv & 31;
  int tid = threadIdx.x;
  float s = 0.f, s2 = 0.f;
  for (int t = tid; t < NSEQ; t += 256) {
    float x = tokens[((size_t)b * NSEQ + t) * NNV + v];
    s += x; s2 += x * x;
  }
  __shared__ float rs[256], rs2[256];
  rs[tid] = s; rs2[tid] = s2;
  __syncthreads();
  for (int o = 128; o; o >>= 1) {
    if (tid < o) { rs[tid] += rs[tid + o]; rs2[tid] += rs2[tid + o]; }
    __syncthreads();
  }
  if (tid == 0) {
    float m = rs[0] / (float)NSEQ;
    float var = rs2[0] / (float)NSEQ - m * m;
    float sd = sqrtf(var + 1e-5f);
    meanb[bv] = m;
    stdevb[bv] = sd;
    invstd[bv] = 1.f / sd;
  }
}

// ---------------------------------------------------------------
// weight convert + transpose: src f32 (K, N) -> bf16 row (rowOff + n*rowStride), col k
// rowStride=2 interleaves two weight matrices column-wise (SwiGLU pairing).
// grid (K/32, N/32), block 256
// ---------------------------------------------------------------
__global__ __launch_bounds__(256) void convt_kernel(const float* __restrict__ S,
                                                    u16* __restrict__ D,
                                                    int K, int N, int rowOff, int rowStride) {
  __shared__ float t[32][33];
  int k0 = blockIdx.x * 32, n0 = blockIdx.y * 32;
  int tx = threadIdx.x & 31, ty = threadIdx.x >> 5;    // ty 0..7
  for (int r = ty; r < 32; r += 8) t[r][tx] = S[(size_t)(k0 + r) * N + n0 + tx];
  __syncthreads();
  for (int r = ty; r < 32; r += 8)
    D[(size_t)(rowOff + (n0 + r) * rowStride) * K + k0 + tx] = f2bf(t[tx][r]);
}

// ---------------------------------------------------------------
// patch embed: one block per (b,p); 32 output rows (v) of 512.
// ---------------------------------------------------------------
__global__ __launch_bounds__(256) void patch_embed(const float* __restrict__ tokens,
                                                   const float* __restrict__ pe_w,
                                                   const float* __restrict__ pe_b,
                                                   const float* __restrict__ meanb,
                                                   const float* __restrict__ invstd,
                                                   float* __restrict__ H) {
  __shared__ float pw[16 * ND];
  __shared__ float pv[32][16];
  int bp = blockIdx.x;                 // b*64+p
  int b = bp >> 6, p = bp & 63;
  int tid = threadIdx.x;
  for (int i = tid; i < 16 * ND; i += 256) pw[i] = pe_w[i];
  for (int idx = tid; idx < 512; idx += 256) {
    int v = idx >> 4, j = idx & 15;
    int t = p * 8 + j;
    if (t > NSEQ - 1) t = NSEQ - 1;    // repeat-last padding
    int bv = b * 32 + v;
    pv[v][j] = (tokens[((size_t)b * NSEQ + t) * NNV + v] - meanb[bv]) * invstd[bv];
  }
  __syncthreads();
  for (int o = tid; o < 32 * ND; o += 256) {
    int v = o >> 9, d = o & 511;
    float acc = pe_b[d];
#pragma unroll
    for (int j = 0; j < 16; j++) acc += pv[v][j] * pw[j * ND + d];
    H[((size_t)bp * 32 + v) * ND + d] = acc;
  }
}

// ---------------------------------------------------------------
// rmsnorm: fp32 rows (x 512) -> bf16 out, 1 wave per row
// ---------------------------------------------------------------
__global__ __launch_bounds__(256) void rmsnorm_bf16(const float* __restrict__ X,
                                                    const float* __restrict__ W,
                                                    u16* __restrict__ Y) {
  int wave = threadIdx.x >> 6, lane = threadIdx.x & 63;
  size_t row = (size_t)blockIdx.x * 4 + wave;
  const float4* xr = (const float4*)(X + row * ND);
  float4 a = xr[lane], b = xr[64 + lane];
  float s = a.x*a.x + a.y*a.y + a.z*a.z + a.w*a.w
          + b.x*b.x + b.y*b.y + b.z*b.z + b.w*b.w;
  for (int o = 1; o < 64; o <<= 1) s += __shfl_xor(s, o);
  float sc = rsqrtf(s * (1.f / ND) + 1e-5f);
  const float4* wr = (const float4*)W;
  float4 wa = wr[lane], wb = wr[64 + lane];
  ushort4 pa, pb;
  pa.x = f2bf(a.x * sc * wa.x); pa.y = f2bf(a.y * sc * wa.y);
  pa.z = f2bf(a.z * sc * wa.z); pa.w = f2bf(a.w * sc * wa.w);
  pb.x = f2bf(b.x * sc * wb.x); pb.y = f2bf(b.y * sc * wb.y);
  pb.z = f2bf(b.z * sc * wb.z); pb.w = f2bf(b.w * sc * wb.w);
  ushort4* yr = (ushort4*)(Y + row * ND);
  yr[lane] = pa; yr[64 + lane] = pb;
}

// rmsnorm + within-batch row permute (p,v)->(v,p), fp32 out to bounce.
// grid (512, GB); batch bb = blockIdx.y
__global__ __launch_bounds__(256) void rms_transpose_batch(const float* __restrict__ X,
                                                           const float* __restrict__ W,
                                                           float* __restrict__ Y) {
  int bb = blockIdx.y;
  X += (size_t)bb * 2048 * ND;
  Y += (size_t)bb * 2048 * ND;
  int wave = threadIdx.x >> 6, lane = threadIdx.x & 63;
  int row = blockIdx.x * 4 + wave;               // 0..2047 = p*32+v
  int p = row >> 5, v = row & 31;
  size_t r2 = (size_t)v * 64 + p;                // v*64+p
  const float4* xr = (const float4*)(X + (size_t)row * ND);
  float4 a = xr[lane], b4 = xr[64 + lane];
  float s = a.x*a.x + a.y*a.y + a.z*a.z + a.w*a.w
          + b4.x*b4.x + b4.y*b4.y + b4.z*b4.z + b4.w*b4.w;
  for (int o = 1; o < 64; o <<= 1) s += __shfl_xor(s, o);
  float sc = rsqrtf(s * (1.f / ND) + 1e-5f);
  const float4* wr = (const float4*)W;
  float4 wa = wr[lane], wb = wr[64 + lane];
  float4 oa, ob;
  oa.x = a.x * sc * wa.x;  oa.y = a.y * sc * wa.y;
  oa.z = a.z * sc * wa.z;  oa.w = a.w * sc * wa.w;
  ob.x = b4.x * sc * wb.x; ob.y = b4.y * sc * wb.y;
  ob.z = b4.z * sc * wb.z; ob.w = b4.w * sc * wb.w;
  float4* yr = (float4*)(Y + r2 * ND);
  yr[lane] = oa; yr[64 + lane] = ob;
}

__global__ __launch_bounds__(256) void copy_f32v4(const float4* __restrict__ S,
                                                  float4* __restrict__ D, int n) {
  int i = blockIdx.x * 256 + threadIdx.x;
  if (i < n) D[i] = S[i];
}

// ---------------------------------------------------------------
// MFMA GEMM: C[M,N] = A[M,K] @ Bt[N,K]^T ; A,Bt bf16(u16), acc fp32.
// MODE 0: store bf16 into Cb (width NOUT==N).
// MODE 1: Hres[M,N] += result (fp32 residual).
// MODE 3: SwiGLU-interleaved: even col=u (W1), odd col=g (W3);
//         even lanes store silu(u)*g at col/2 into Cb (width NOUT==N/2).
// block 256 = 4 waves (2x2 of 64x64), tile 128x128.
// K-loop: 64 per barrier-pair as two BK=32 half-buffers (keeps the verified
// contiguous global_load_lds layout; halves barrier-drain count vs BK=32).
// grid (N/128, M/128); K % 64 == 0.
// ---------------------------------------------------------------
template<int MODE>
__global__ __launch_bounds__(256) void gemm_bt(const u16* __restrict__ A,
                                               const u16* __restrict__ Bt,
                                               u16* __restrict__ Cb,
                                               float* __restrict__ Hres,
                                               int N, int K, int NOUT) {
  __shared__ u16 lA[2][128 * 32];
  __shared__ u16 lB[2][128 * 32];
  const int tid = threadIdx.x;
  const int lane = tid & 63;
  const int w = tid >> 6;
  const int wm = (w >> 1) * 64, wn = (w & 1) * 64;
  const int m0 = blockIdx.y * 128, n0 = blockIdx.x * 128;
  const int rowL = tid >> 2;            // 0..63
  const int colL = (tid & 3) * 8;       // k element offset within a 32-half
  const int mfm = lane & 15, mfk = (lane >> 4) * 8;

  const u16* pA0 = A + (size_t)(m0 + rowL) * K + colL;
  const u16* pA1 = pA0 + (size_t)64 * K;
  const u16* pB0 = Bt + (size_t)(n0 + rowL) * K + colL;
  const u16* pB1 = pB0 + (size_t)64 * K;

  f32x4 acc[4][4] = {};

  for (int k0 = 0; k0 < K; k0 += 64) {
    __syncthreads();                    // prev iter's LDS reads done
#pragma unroll
    for (int hh = 0; hh < 2; hh++) {
      int kk = k0 + hh * 32;
      gload16(pA0 + kk, lA[hh] + w * 512);
      gload16(pA1 + kk, lA[hh] + 2048 + w * 512);
      gload16(pB0 + kk, lB[hh] + w * 512);
      gload16(pB1 + kk, lB[hh] + 2048 + w * 512);
    }
    __syncthreads();                    // staging complete (vmcnt drained)
#pragma unroll
    for (int hh = 0; hh < 2; hh++) {
      short8 af[4], bfr[4];
#pragma unroll
      for (int i = 0; i < 4; i++) {
        af[i]  = *(const short8*)(lA[hh] + (wm + i * 16 + mfm) * 32 + mfk);
        bfr[i] = *(const short8*)(lB[hh] + (wn + i * 16 + mfm) * 32 + mfk);
      }
#pragma unroll
      for (int mi = 0; mi < 4; mi++)
#pragma unroll
        for (int ni = 0; ni < 4; ni++)
          acc[mi][ni] = __builtin_amdgcn_mfma_f32_16x16x32_bf16(af[mi], bfr[ni], acc[mi][ni], 0, 0, 0);
    }
  }

  const int cr = (lane >> 4) * 4, cc = lane & 15;
#pragma unroll
  for (int mi = 0; mi < 4; mi++) {
#pragma unroll
    for (int ni = 0; ni < 4; ni++) {
#pragma unroll
      for (int i = 0; i < 4; i++) {
        int r = m0 + wm + mi * 16 + cr + i;
        int c = n0 + wn + ni * 16 + cc;
        if (MODE == 1) {
          Hres[(size_t)r * N + c] += acc[mi][ni][i];
        } else if (MODE == 3) {
          float mine = acc[mi][ni][i];
          float other = __shfl_xor(mine, 1);
          if ((lane & 1) == 0) {        // even lane holds u (W1), partner g (W3)
            float u = mine;
            Cb[(size_t)r * NOUT + (c >> 1)] = f2bf(u / (1.f + __expf(-u)) * other);
          }
        } else {
          Cb[(size_t)r * NOUT + c] = f2bf(acc[mi][ni][i]);
        }
      }
    }
  }
}

// ---------------------------------------------------------------
// attention: one block per (head, group). QKV rows are 1536 wide
// [q|k|v], head slice 64. S=32 (rel) or S=64 (enc: rope + causal).
// ---------------------------------------------------------------
template<int S, bool ROPE>
__global__ __launch_bounds__(256) void attn_kernel(const u16* __restrict__ QKV,
                                                   u16* __restrict__ O) {
  __shared__ float qs[S][64];
  __shared__ float kbuf[S][65];       // padded rows; reused as v[S][64]
  __shared__ float ps[S][S];
  int h = blockIdx.x, bb = blockIdx.y, tid = threadIdx.x;
  size_t base = ((size_t)bb * S) * 1536 + h * 64;

  for (int idx = tid; idx < S * 64; idx += 256) {
    int s = idx >> 6, d = idx & 63;
    size_t o = base + (size_t)s * 1536 + d;
    qs[s][d] = bf2f(QKV[o]);
    kbuf[s][d] = bf2f(QKV[o + 512]);
  }
  __syncthreads();

  if (ROPE) {
    for (int idx = tid; idx < S * 32; idx += 256) {
      int s = idx >> 5, i = idx & 31;
      float inv = powf(10000.f, -(float)i * (1.f / 32.f));   // 10000^(-2i/64)
      float ang = (float)s * inv;
      float sn, cn;
      sincosf(ang, &sn, &cn);
      float xr = qs[s][2 * i], xi = qs[s][2 * i + 1];
      qs[s][2 * i] = xr * cn - xi * sn;
      qs[s][2 * i + 1] = xr * sn + xi * cn;
      xr = kbuf[s][2 * i]; xi = kbuf[s][2 * i + 1];
      kbuf[s][2 * i] = xr * cn - xi * sn;
      kbuf[s][2 * i + 1] = xr * sn + xi * cn;
    }
    __syncthreads();
  }

  constexpr int JG = S / 4;
  for (int idx = tid; idx < S * JG; idx += 256) {
    int i = idx / JG, j0 = (idx % JG) * 4;
    float a0 = 0, a1 = 0, a2 = 0, a3 = 0;
#pragma unroll 8
    for (int d = 0; d < 64; d++) {
      float q = qs[i][d];
      a0 += q * kbuf[j0 + 0][d];
      a1 += q * kbuf[j0 + 1][d];
      a2 += q * kbuf[j0 + 2][d];
      a3 += q * kbuf[j0 + 3][d];
    }
    const float sc = 0.125f;            // 1/sqrt(64)
    float4 r;
    if (ROPE) {
      r.x = (j0 + 0 <= i) ? a0 * sc : -1e30f;
      r.y = (j0 + 1 <= i) ? a1 * sc : -1e30f;
      r.z = (j0 + 2 <= i) ? a2 * sc : -1e30f;
      r.w = (j0 + 3 <= i) ? a3 * sc : -1e30f;
    } else {
      r.x = a0 * sc; r.y = a1 * sc; r.z = a2 * sc; r.w = a3 * sc;
    }
    *(float4*)&ps[i][j0] = r;
  }
  __syncthreads();

  // overwrite k's LDS with v (flat [S][64]); softmax runs concurrently on ps
  float* vs = &kbuf[0][0];
  for (int idx = tid; idx < S * 64; idx += 256) {
    int s = idx >> 6, d = idx & 63;
    vs[idx] = bf2f(QKV[base + (size_t)s * 1536 + 1024 + d]);
  }
  if (tid < S) {
    float m = -1e30f;
    for (int j = 0; j < S; j++) m = fmaxf(m, ps[tid][j]);
    float sum = 0.f;
    for (int j = 0; j < S; j++) {
      float e = __expf(ps[tid][j] - m);
      ps[tid][j] = e; sum += e;
    }
    float r = 1.f / sum;
    for (int j = 0; j < S; j++) ps[tid][j] *= r;
  }
  __syncthreads();

  for (int idx = tid; idx < S * 16; idx += 256) {
    int s = idx >> 4, d0 = (idx & 15) * 4;
    float a0 = 0, a1 = 0, a2 = 0, a3 = 0;
#pragma unroll 8
    for (int j = 0; j < S; j++) {
      float p = ps[s][j];
      const float* vr = vs + j * 64 + d0;
      a0 += p * vr[0]; a1 += p * vr[1]; a2 += p * vr[2]; a3 += p * vr[3];
    }
    size_t oo = ((size_t)bb * S + s) * 512 + h * 64 + d0;
    ushort4 pk;
    pk.x = f2bf(a0); pk.y = f2bf(a1); pk.z = f2bf(a2); pk.w = f2bf(a3);
    *(ushort4*)(O + oo) = pk;
  }
}

__global__ __launch_bounds__(256) void zero_f32(float* __restrict__ p, int n) {
  int i = blockIdx.x * 256 + threadIdx.x;
  if (i < n) p[i] = 0.f;
}

// ---------------------------------------------------------------
// head GEMM (per row-chunk): Z[rows,96] += A[rows,32768] @ Bt[96,32768]^T
// grid (rows/64 m-tiles, 32 k-chunks of 1024), block 256 = 4 waves
// ---------------------------------------------------------------
__global__ __launch_bounds__(256) void head_gemm(const u16* __restrict__ A,
                                                 const u16* __restrict__ Bt,
                                                 float* __restrict__ Z) {
  __shared__ u16 lA[64 * 32];
  __shared__ u16 lB[96 * 32];
  int tid = threadIdx.x, lane = tid & 63, w = tid >> 6;
  int m0 = blockIdx.x * 64;
  int kbase = blockIdx.y * 1024;
  const int mfm = lane & 15, mfk = (lane >> 4) * 8;
  f32x4 acc[6] = {};

  for (int kk = 0; kk < 1024; kk += 32) {
    int k0 = kbase + kk;
    uint4 a0 = *(const uint4*)(A + (size_t)(m0 + (tid >> 2)) * 32768 + k0 + (tid & 3) * 8);
    uint4 b0 = *(const uint4*)(Bt + (size_t)(tid >> 2) * 32768 + k0 + (tid & 3) * 8);
    uint4 b1;
    bool has2 = tid < 128;
    int slot2 = 256 + tid, row2 = slot2 >> 2, c82 = (slot2 & 3) * 8;
    if (has2) b1 = *(const uint4*)(Bt + (size_t)row2 * 32768 + k0 + c82);
    __syncthreads();
    *(uint4*)(lA + (tid >> 2) * 32 + (tid & 3) * 8) = a0;
    *(uint4*)(lB + (tid >> 2) * 32 + (tid & 3) * 8) = b0;
    if (has2) *(uint4*)(lB + row2 * 32 + c82) = b1;
    __syncthreads();
    short8 af = *(const short8*)(lA + (w * 16 + mfm) * 32 + mfk);
#pragma unroll
    for (int nt = 0; nt < 6; nt++) {
      short8 bfr = *(const short8*)(lB + (nt * 16 + mfm) * 32 + mfk);
      acc[nt] = __builtin_amdgcn_mfma_f32_16x16x32_bf16(af, bfr, acc[nt], 0, 0, 0);
    }
  }
  int cr = (lane >> 4) * 4, cc = lane & 15;
#pragma unroll
  for (int nt = 0; nt < 6; nt++)
#pragma unroll
    for (int i = 0; i < 4; i++)
      atomicAdd(&Z[(size_t)(m0 + w * 16 + cr + i) * NPRED + nt * 16 + cc], acc[nt][i]);
}

// out[b,t,v] = (Z[b*32+v, t] + head_b[t]) * stdev[b,v] + mean[b,v]
__global__ __launch_bounds__(256) void final_kernel(const float* __restrict__ Z,
                                                    const float* __restrict__ head_b,
                                                    const float* __restrict__ meanb,
                                                    const float* __restrict__ stdevb,
                                                    float* __restrict__ out) {
  int idx = blockIdx.x * 256 + threadIdx.x;
  if (idx >= NBS * NPRED * NNV) return;
  int v = idx & 31;
  int t = (idx >> 5) % NPRED;
  int b = idx / (NPRED * NNV);
  int bv = b * 32 + v;
  out[idx] = (Z[(size_t)bv * NPRED + t] + head_b[t]) * stdevb[bv] + meanb[bv];
}

// ---------------------------------------------------------------
extern "C" void kernel_launch(void* const* d_in, const int* in_sizes, int n_in,
                              void* d_out, int out_size, void* d_ws, size_t ws_size,
                              hipStream_t stream) {
  const float* tokens = (const float*)d_in[0];
  const float* pe_w   = (const float*)d_in[1];
  const float* pe_b   = (const float*)d_in[2];
  const float* norm_w = (const float*)d_in[3];
  const float* head_w = (const float*)d_in[4];
  const float* head_b = (const float*)d_in[5];
  const float* wq[2] = {(const float*)d_in[6],  (const float*)d_in[15]};
  const float* wk[2] = {(const float*)d_in[7],  (const float*)d_in[16]};
  const float* wv[2] = {(const float*)d_in[8],  (const float*)d_in[17]};
  const float* wo[2] = {(const float*)d_in[9],  (const float*)d_in[18]};
  const float* w1[2] = {(const float*)d_in[10], (const float*)d_in[19]};
  const float* w2[2] = {(const float*)d_in[11], (const float*)d_in[20]};
  const float* w3[2] = {(const float*)d_in[12], (const float*)d_in[21]};
  const float* an[2] = {(const float*)d_in[13], (const float*)d_in[22]};
  const float* fn[2] = {(const float*)d_in[14], (const float*)d_in[23]};

  char* ws = (char*)d_ws;
  size_t off = 0;
  auto alloc = [&](size_t bytes) -> void* {
    void* p = ws + off;
    off += (bytes + 255) & ~(size_t)255;
    return p;
  };
  // ~215 MB total workspace
  float* meanb  = (float*)alloc(1024 * 4);
  float* invstd = (float*)alloc(1024 * 4);
  float* stdevb = (float*)alloc(1024 * 4);
  u16* wl_qkv = (u16*)alloc((size_t)1536 * 512 * 2);    // current layer only
  u16* wl_o   = (u16*)alloc((size_t)512 * 512 * 2);
  u16* wl_13  = (u16*)alloc((size_t)3072 * 512 * 2);    // W1/W3 column-interleaved
  u16* wl_2   = (u16*)alloc((size_t)512 * 1536 * 2);
  u16* hw_t   = (u16*)alloc((size_t)96 * 32768 * 2);
  float* z    = (float*)alloc((size_t)1024 * 96 * 4);
  float* h    = (float*)alloc((size_t)MROWS * ND * 4);          // 134 MB residual
  u16* xn     = (u16*)alloc((size_t)RCHUNK * ND * 2);           // 16.8 MB (rmsnorm out / attn out)
  u16* g1     = (u16*)alloc((size_t)RCHUNK * NHID * 2);         // 50.3 MB
  float* bounce = (float*)g1;   // 8*2048*512*4 = 33.5 MB, overlays dead g1

  stats_kernel<<<1024, 256, 0, stream>>>(tokens, meanb, invstd, stdevb);
  convt_kernel<<<dim3(1024, 3), 256, 0, stream>>>(head_w, hw_t, 32768, 96, 0, 1);
  patch_embed<<<2048, 256, 0, stream>>>(tokens, pe_w, pe_b, meanb, invstd, h);

  for (int l = 0; l < 8; l++) {
    int ph = l >> 2, li = l & 3;
    // convert this layer's weights to bf16 transposed (N x K)
    convt_kernel<<<dim3(16, 16), 256, 0, stream>>>(wq[ph] + (size_t)li * 512 * 512, wl_qkv, 512, 512, 0, 1);
    convt_kernel<<<dim3(16, 16), 256, 0, stream>>>(wk[ph] + (size_t)li * 512 * 512, wl_qkv, 512, 512, 512, 1);
    convt_kernel<<<dim3(16, 16), 256, 0, stream>>>(wv[ph] + (size_t)li * 512 * 512, wl_qkv, 512, 512, 1024, 1);
    convt_kernel<<<dim3(16, 16), 256, 0, stream>>>(wo[ph] + (size_t)li * 512 * 512, wl_o, 512, 512, 0, 1);
    convt_kernel<<<dim3(16, 48), 256, 0, stream>>>(w1[ph] + (size_t)li * 512 * 1536, wl_13, 512, 1536, 0, 2);
    convt_kernel<<<dim3(16, 48), 256, 0, stream>>>(w3[ph] + (size_t)li * 512 * 1536, wl_13, 512, 1536, 1, 2);
    convt_kernel<<<dim3(48, 16), 256, 0, stream>>>(w2[ph] + (size_t)li * 1536 * 512, wl_2, 1536, 512, 0, 1);
    const float* anl = an[ph] + li * 512;
    const float* fnl = fn[ph] + li * 512;

    for (int c = 0; c < NCHUNK; c++) {
      float* hc = h + (size_t)c * RCHUNK * ND;
      rmsnorm_bf16<<<RCHUNK / 4, 256, 0, stream>>>(hc, anl, xn);
      gemm_bt<0><<<dim3(12, RCHUNK / 128), 256, 0, stream>>>(xn, wl_qkv, g1, (float*)nullptr, 1536, 512, 1536);
      // attention output overlays xn (dead after qkv GEMM)
      if (ph == 0) attn_kernel<32, false><<<dim3(8, RCHUNK / 32), 256, 0, stream>>>(g1, xn);
      else         attn_kernel<64, true ><<<dim3(8, RCHUNK / 64), 256, 0, stream>>>(g1, xn);
      gemm_bt<1><<<dim3(4, RCHUNK / 128), 256, 0, stream>>>(xn, wl_o, (u16*)nullptr, hc, 512, 512, 512);
      rmsnorm_bf16<<<RCHUNK / 4, 256, 0, stream>>>(hc, fnl, xn);
      // fused W1|W3 (column-interleaved) + SwiGLU epilogue -> g1 (M x 1536)
      gemm_bt<3><<<dim3(24, RCHUNK / 128), 256, 0, stream>>>(xn, wl_13, g1, (float*)nullptr, 3072, 512, 1536);
      gemm_bt<1><<<dim3(4, RCHUNK / 128), 256, 0, stream>>>(g1, wl_2, (u16*)nullptr, hc, 512, 1536, 512);
    }

    if (l == 3) {
      // rel->enc handoff: rms_norm + within-batch (p,v)->(v,p) row permute,
      // 8 batches per round through the 33.5 MB bounce (g1 space is dead)
      for (int g = 0; g < 4; g++) {
        float* hg = h + (size_t)g * 8 * 2048 * ND;
        rms_transpose_batch<<<dim3(512, 8), 256, 0, stream>>>(hg, norm_w, bounce);
        copy_f32v4<<<8192, 256, 0, stream>>>((const float4*)bounce, (float4*)hg, 8 * 2048 * ND / 4);
      }
    }
  }

  // head: per-chunk rmsnorm -> 256 complete M-rows of the 1024x96x32768 GEMM
  zero_f32<<<384, 256, 0, stream>>>(z, 1024 * 96);
  for (int c = 0; c < NCHUNK; c++) {
    rmsnorm_bf16<<<RCHUNK / 4, 256, 0, stream>>>(h + (size_t)c * RCHUNK * ND, norm_w, xn);
    head_gemm<<<dim3(RCHUNK / 64 / 64, 32), 256, 0, stream>>>(xn, hw_t, z + (size_t)c * (RCHUNK / 64) * NPRED);
  }
  final_kernel<<<384, 256, 0, stream>>>(z, head_b, meanb, stdevb, (float*)d_out);
}

// Round 5
// 8735.322 us; speedup vs baseline: 1.6633x; 1.1950x over previous
//
#include <hip/hip_runtime.h>

using u16 = unsigned short;
typedef float f32x4 __attribute__((ext_vector_type(4)));
typedef short short8 __attribute__((ext_vector_type(8)));

// ---------- bf16 helpers (buffers held as u16; RNE conversion) ----------
__device__ __forceinline__ float bf2f(u16 u) {
  return __uint_as_float(((unsigned)u) << 16);
}
__device__ __forceinline__ u16 f2bf(float f) {
  unsigned u = __float_as_uint(f);
  unsigned r = u + 0x7fffu + ((u >> 16) & 1u);
  return (u16)(r >> 16);
}

// async global->LDS, 16B per lane; LDS dest is wave-uniform base + lane*16
__device__ __forceinline__ void gload16(const void* g, void* l) {
  __builtin_amdgcn_global_load_lds(
      reinterpret_cast<const __attribute__((address_space(1))) unsigned int*>(
          reinterpret_cast<uintptr_t>(g)),
      reinterpret_cast<__attribute__((address_space(3))) unsigned int*>(
          reinterpret_cast<uintptr_t>(l)),
      16, 0, 0);
}

// model constants
#define NBS 32
#define NSEQ 512
#define NNV 32
#define ND 512
#define NHID 1536
#define NPNUM 64
#define NPRED 96
#define MROWS 65536           // tokens per phase
#define RCHUNK 16384          // row chunk (multiple of 64)
#define NCHUNK (MROWS / RCHUNK)

// ---------------------------------------------------------------
// per-(b,v) mean / stdev over SEQ
// ---------------------------------------------------------------
__global__ __launch_bounds__(256) void stats_kernel(const float* __restrict__ tokens,
                                                    float* __restrict__ meanb,
                                                    float* __restrict__ invstd,
                                                    float* __restrict__ stdevb) {
  int bv = blockIdx.x;            // 0..1023
  int b = bv >> 5, v = bv & 31;
  int tid = threadIdx.x;
  float s = 0.f, s2 = 0.f;
  for (int t = tid; t < NSEQ; t += 256) {
    float x = tokens[((size_t)b * NSEQ + t) * NNV + v];
    s += x; s2 += x * x;
  }
  __shared__ float rs[256], rs2[256];
  rs[tid] = s; rs2[tid] = s2;
  __syncthreads();
  for (int o = 128; o; o >>= 1) {
    if (tid < o) { rs[tid] += rs[tid + o]; rs2[tid] += rs2[tid + o]; }
    __syncthreads();
  }
  if (tid == 0) {
    float m = rs[0] / (float)NSEQ;
    float var = rs2[0] / (float)NSEQ - m * m;
    float sd = sqrtf(var + 1e-5f);
    meanb[bv] = m;
    stdevb[bv] = sd;
    invstd[bv] = 1.f / sd;
  }
}

// ---------------------------------------------------------------
// weight convert + transpose: src f32 (K, N) -> bf16 row (rowOff + n*rowStride), col k
// rowStride=2 interleaves two weight matrices column-wise (SwiGLU pairing).
// grid (K/32, N/32), block 256
// ---------------------------------------------------------------
__global__ __launch_bounds__(256) void convt_kernel(const float* __restrict__ S,
                                                    u16* __restrict__ D,
                                                    int K, int N, int rowOff, int rowStride) {
  __shared__ float t[32][33];
  int k0 = blockIdx.x * 32, n0 = blockIdx.y * 32;
  int tx = threadIdx.x & 31, ty = threadIdx.x >> 5;    // ty 0..7
  for (int r = ty; r < 32; r += 8) t[r][tx] = S[(size_t)(k0 + r) * N + n0 + tx];
  __syncthreads();
  for (int r = ty; r < 32; r += 8)
    D[(size_t)(rowOff + (n0 + r) * rowStride) * K + k0 + tx] = f2bf(t[tx][r]);
}

// ---------------------------------------------------------------
// patch embed: one block per (b,p); 32 output rows (v) of 512.
// ---------------------------------------------------------------
__global__ __launch_bounds__(256) void patch_embed(const float* __restrict__ tokens,
                                                   const float* __restrict__ pe_w,
                                                   const float* __restrict__ pe_b,
                                                   const float* __restrict__ meanb,
                                                   const float* __restrict__ invstd,
                                                   float* __restrict__ H) {
  __shared__ float pw[16 * ND];
  __shared__ float pv[32][16];
  int bp = blockIdx.x;                 // b*64+p
  int b = bp >> 6, p = bp & 63;
  int tid = threadIdx.x;
  for (int i = tid; i < 16 * ND; i += 256) pw[i] = pe_w[i];
  for (int idx = tid; idx < 512; idx += 256) {
    int v = idx >> 4, j = idx & 15;
    int t = p * 8 + j;
    if (t > NSEQ - 1) t = NSEQ - 1;    // repeat-last padding
    int bv = b * 32 + v;
    pv[v][j] = (tokens[((size_t)b * NSEQ + t) * NNV + v] - meanb[bv]) * invstd[bv];
  }
  __syncthreads();
  for (int o = tid; o < 32 * ND; o += 256) {
    int v = o >> 9, d = o & 511;
    float acc = pe_b[d];
#pragma unroll
    for (int j = 0; j < 16; j++) acc += pv[v][j] * pw[j * ND + d];
    H[((size_t)bp * 32 + v) * ND + d] = acc;
  }
}

// ---------------------------------------------------------------
// rmsnorm: fp32 rows (x 512) -> bf16 out, 1 wave per row
// ---------------------------------------------------------------
__global__ __launch_bounds__(256) void rmsnorm_bf16(const float* __restrict__ X,
                                                    const float* __restrict__ W,
                                                    u16* __restrict__ Y) {
  int wave = threadIdx.x >> 6, lane = threadIdx.x & 63;
  size_t row = (size_t)blockIdx.x * 4 + wave;
  const float4* xr = (const float4*)(X + row * ND);
  float4 a = xr[lane], b = xr[64 + lane];
  float s = a.x*a.x + a.y*a.y + a.z*a.z + a.w*a.w
          + b.x*b.x + b.y*b.y + b.z*b.z + b.w*b.w;
  for (int o = 1; o < 64; o <<= 1) s += __shfl_xor(s, o);
  float sc = rsqrtf(s * (1.f / ND) + 1e-5f);
  const float4* wr = (const float4*)W;
  float4 wa = wr[lane], wb = wr[64 + lane];
  ushort4 pa, pb;
  pa.x = f2bf(a.x * sc * wa.x); pa.y = f2bf(a.y * sc * wa.y);
  pa.z = f2bf(a.z * sc * wa.z); pa.w = f2bf(a.w * sc * wa.w);
  pb.x = f2bf(b.x * sc * wb.x); pb.y = f2bf(b.y * sc * wb.y);
  pb.z = f2bf(b.z * sc * wb.z); pb.w = f2bf(b.w * sc * wb.w);
  ushort4* yr = (ushort4*)(Y + row * ND);
  yr[lane] = pa; yr[64 + lane] = pb;
}

// rmsnorm + within-batch row permute (p,v)->(v,p), fp32 out to bounce.
// grid (512, GB); batch bb = blockIdx.y
__global__ __launch_bounds__(256) void rms_transpose_batch(const float* __restrict__ X,
                                                           const float* __restrict__ W,
                                                           float* __restrict__ Y) {
  int bb = blockIdx.y;
  X += (size_t)bb * 2048 * ND;
  Y += (size_t)bb * 2048 * ND;
  int wave = threadIdx.x >> 6, lane = threadIdx.x & 63;
  int row = blockIdx.x * 4 + wave;               // 0..2047 = p*32+v
  int p = row >> 5, v = row & 31;
  size_t r2 = (size_t)v * 64 + p;                // v*64+p
  const float4* xr = (const float4*)(X + (size_t)row * ND);
  float4 a = xr[lane], b4 = xr[64 + lane];
  float s = a.x*a.x + a.y*a.y + a.z*a.z + a.w*a.w
          + b4.x*b4.x + b4.y*b4.y + b4.z*b4.z + b4.w*b4.w;
  for (int o = 1; o < 64; o <<= 1) s += __shfl_xor(s, o);
  float sc = rsqrtf(s * (1.f / ND) + 1e-5f);
  const float4* wr = (const float4*)W;
  float4 wa = wr[lane], wb = wr[64 + lane];
  float4 oa, ob;
  oa.x = a.x * sc * wa.x;  oa.y = a.y * sc * wa.y;
  oa.z = a.z * sc * wa.z;  oa.w = a.w * sc * wa.w;
  ob.x = b4.x * sc * wb.x; ob.y = b4.y * sc * wb.y;
  ob.z = b4.z * sc * wb.z; ob.w = b4.w * sc * wb.w;
  float4* yr = (float4*)(Y + r2 * ND);
  yr[lane] = oa; yr[64 + lane] = ob;
}

__global__ __launch_bounds__(256) void copy_f32v4(const float4* __restrict__ S,
                                                  float4* __restrict__ D, int n) {
  int i = blockIdx.x * 256 + threadIdx.x;
  if (i < n) D[i] = S[i];
}

// ---------------------------------------------------------------
// MFMA GEMM: C[M,N] = A[M,K] @ Bt[N,K]^T ; A,Bt bf16(u16), acc fp32.
// MODE 0: store bf16 into Cb (width NOUT==N).
// MODE 1: Hres[M,N] += result (fp32 residual).
// MODE 3: SwiGLU-interleaved: even col=u (W1), odd col=g (W3);
//         even lanes store silu(u)*g at col/2 into Cb (width NOUT==N/2).
// block 256 = 4 waves (2x2 of 64x64), tile 128x128, K per barrier = 64.
// grid (N/128, M/128); K % 64 == 0.
// ---------------------------------------------------------------
template<int MODE>
__global__ __launch_bounds__(256) void gemm_bt(const u16* __restrict__ A,
                                               const u16* __restrict__ Bt,
                                               u16* __restrict__ Cb,
                                               float* __restrict__ Hres,
                                               int N, int K, int NOUT) {
  __shared__ u16 lA[2][128 * 32];
  __shared__ u16 lB[2][128 * 32];
  const int tid = threadIdx.x;
  const int lane = tid & 63;
  const int w = tid >> 6;
  const int wm = (w >> 1) * 64, wn = (w & 1) * 64;
  const int m0 = blockIdx.y * 128, n0 = blockIdx.x * 128;
  const int rowL = tid >> 2;            // 0..63
  const int colL = (tid & 3) * 8;       // k element offset within a 32-half
  const int mfm = lane & 15, mfk = (lane >> 4) * 8;

  const u16* pA0 = A + (size_t)(m0 + rowL) * K + colL;
  const u16* pA1 = pA0 + (size_t)64 * K;
  const u16* pB0 = Bt + (size_t)(n0 + rowL) * K + colL;
  const u16* pB1 = pB0 + (size_t)64 * K;

  f32x4 acc[4][4] = {};

  for (int k0 = 0; k0 < K; k0 += 64) {
    __syncthreads();                    // prev iter's LDS reads done
#pragma unroll
    for (int hh = 0; hh < 2; hh++) {
      int kk = k0 + hh * 32;
      gload16(pA0 + kk, lA[hh] + w * 512);
      gload16(pA1 + kk, lA[hh] + 2048 + w * 512);
      gload16(pB0 + kk, lB[hh] + w * 512);
      gload16(pB1 + kk, lB[hh] + 2048 + w * 512);
    }
    __syncthreads();                    // staging complete (vmcnt drained)
#pragma unroll
    for (int hh = 0; hh < 2; hh++) {
      short8 af[4], bfr[4];
#pragma unroll
      for (int i = 0; i < 4; i++) {
        af[i]  = *(const short8*)(lA[hh] + (wm + i * 16 + mfm) * 32 + mfk);
        bfr[i] = *(const short8*)(lB[hh] + (wn + i * 16 + mfm) * 32 + mfk);
      }
#pragma unroll
      for (int mi = 0; mi < 4; mi++)
#pragma unroll
        for (int ni = 0; ni < 4; ni++)
          acc[mi][ni] = __builtin_amdgcn_mfma_f32_16x16x32_bf16(af[mi], bfr[ni], acc[mi][ni], 0, 0, 0);
    }
  }

  const int cr = (lane >> 4) * 4, cc = lane & 15;
#pragma unroll
  for (int mi = 0; mi < 4; mi++) {
#pragma unroll
    for (int ni = 0; ni < 4; ni++) {
#pragma unroll
      for (int i = 0; i < 4; i++) {
        int r = m0 + wm + mi * 16 + cr + i;
        int c = n0 + wn + ni * 16 + cc;
        if (MODE == 1) {
          Hres[(size_t)r * N + c] += acc[mi][ni][i];
        } else if (MODE == 3) {
          float mine = acc[mi][ni][i];
          float other = __shfl_xor(mine, 1);
          if ((lane & 1) == 0) {        // even lane holds u (W1), partner g (W3)
            float u = mine;
            Cb[(size_t)r * NOUT + (c >> 1)] = f2bf(u / (1.f + __expf(-u)) * other);
          }
        } else {
          Cb[(size_t)r * NOUT + c] = f2bf(acc[mi][ni][i]);
        }
      }
    }
  }
}

// ---------------------------------------------------------------
// MFMA attention: one block per (head, group). QKV rows 1536 wide [q|k|v],
// head slice 64. S=32 (rel): 2 waves; S=64 (enc: rope+causal): 4 waves.
// QK^T and PV use the same A@Bt^T fragment convention as gemm_bt (verified).
// Softmax fully in-register (row cols live in one quad across acc tiles).
// P goes C-layout -> A-layout via wave-local LDS bounce (bf16).
// LDS rows padded to 68 u16 (136B) -> 2-way bank aliasing only (free).
// ---------------------------------------------------------------
template<int S, bool ROPE>
__global__ __launch_bounds__(64 * (S / 16)) void attn_mfma(const u16* __restrict__ QKV,
                                                           u16* __restrict__ O) {
  constexpr int WAVES = S / 16;
  constexpr int NT = S / 16;          // score col tiles
  constexpr int LDW = 68;             // padded LDS row stride (u16)
  constexpr int T = 64 * WAVES;
  __shared__ u16 qs[S * LDW];
  __shared__ u16 ks[S * LDW];
  __shared__ u16 vt[64 * LDW];        // vt[d][j] = V[j][d]
  __shared__ u16 pbuf[S * LDW];
  int h = blockIdx.x, bb = blockIdx.y, tid = threadIdx.x;
  const int lane = tid & 63, w = tid >> 6;
  const int mfm = lane & 15, quad = lane >> 4;
  const int m0 = w * 16;
  size_t base = ((size_t)bb * S) * 1536 + h * 64;

  // load q,k (rope applied in fp32), v transposed
  for (int idx = tid; idx < S * 16; idx += T) {
    int s = idx >> 4, c4 = (idx & 15) * 4;
    const u16* rowp = QKV + base + (size_t)s * 1536;
    ushort4 qv = *(const ushort4*)(rowp + c4);
    ushort4 kv = *(const ushort4*)(rowp + 512 + c4);
    if (ROPE) {
      int i0 = c4 >> 1;               // rope pair indices i0, i0+1
      float inv0 = powf(10000.f, -(float)i0 * (1.f / 32.f));
      float inv1 = powf(10000.f, -(float)(i0 + 1) * (1.f / 32.f));
      float sn0, cn0, sn1, cn1;
      sincosf((float)s * inv0, &sn0, &cn0);
      sincosf((float)s * inv1, &sn1, &cn1);
      float q0 = bf2f(qv.x), q1 = bf2f(qv.y), q2 = bf2f(qv.z), q3 = bf2f(qv.w);
      float k0 = bf2f(kv.x), k1 = bf2f(kv.y), k2 = bf2f(kv.z), k3 = bf2f(kv.w);
      qv.x = f2bf(q0 * cn0 - q1 * sn0); qv.y = f2bf(q0 * sn0 + q1 * cn0);
      qv.z = f2bf(q2 * cn1 - q3 * sn1); qv.w = f2bf(q2 * sn1 + q3 * cn1);
      kv.x = f2bf(k0 * cn0 - k1 * sn0); kv.y = f2bf(k0 * sn0 + k1 * cn0);
      kv.z = f2bf(k2 * cn1 - k3 * sn1); kv.w = f2bf(k2 * sn1 + k3 * cn1);
    }
    *(ushort4*)(qs + s * LDW + c4) = qv;
    *(ushort4*)(ks + s * LDW + c4) = kv;
    ushort4 vv = *(const ushort4*)(rowp + 1024 + c4);
    vt[(c4 + 0) * LDW + s] = vv.x;
    vt[(c4 + 1) * LDW + s] = vv.y;
    vt[(c4 + 2) * LDW + s] = vv.z;
    vt[(c4 + 3) * LDW + s] = vv.w;
  }
  __syncthreads();

  // scores: sc[nt] = Q[m0..m0+15,:] @ K[nt*16..,:]^T  (K-dim = 64)
  f32x4 sc[NT] = {};
#pragma unroll
  for (int half = 0; half < 64; half += 32) {
    short8 af = *(const short8*)(qs + (m0 + mfm) * LDW + half + quad * 8);
#pragma unroll
    for (int nt = 0; nt < NT; nt++) {
      short8 bf = *(const short8*)(ks + (nt * 16 + mfm) * LDW + half + quad * 8);
      sc[nt] = __builtin_amdgcn_mfma_f32_16x16x32_bf16(af, bf, sc[nt], 0, 0, 0);
    }
  }

  // in-register softmax: row r = m0+quad*4+i; its 64 cols = 16 quad-lanes x NT accs
#pragma unroll
  for (int i = 0; i < 4; i++) {
    int grow = m0 + quad * 4 + i;
    float mx = -1e30f;
#pragma unroll
    for (int nt = 0; nt < NT; nt++) {
      float v = sc[nt][i] * 0.125f;                      // 1/sqrt(64)
      if (ROPE && (nt * 16 + mfm) > grow) v = -1e30f;    // causal
      sc[nt][i] = v;
      mx = fmaxf(mx, v);
    }
#pragma unroll
    for (int o = 1; o < 16; o <<= 1) mx = fmaxf(mx, __shfl_xor(mx, o));
    float sum = 0.f;
#pragma unroll
    for (int nt = 0; nt < NT; nt++) {
      float e = __expf(sc[nt][i] - mx);
      sc[nt][i] = e;
      sum += e;
    }
#pragma unroll
    for (int o = 1; o < 16; o <<= 1) sum += __shfl_xor(sum, o);
    float r = 1.f / sum;
#pragma unroll
    for (int nt = 0; nt < NT; nt++)
      pbuf[grow * LDW + nt * 16 + mfm] = f2bf(sc[nt][i] * r);
  }
  // PV uses only this wave's own P rows (m0..m0+15) -> no barrier needed;
  // compiler orders the ds_write->ds_read dependency via lgkmcnt.

  f32x4 ov[4] = {};
#pragma unroll
  for (int half = 0; half < S; half += 32) {
    short8 af = *(const short8*)(pbuf + (m0 + mfm) * LDW + half + quad * 8);
#pragma unroll
    for (int dt = 0; dt < 4; dt++) {
      short8 bf = *(const short8*)(vt + (dt * 16 + mfm) * LDW + half + quad * 8);
      ov[dt] = __builtin_amdgcn_mfma_f32_16x16x32_bf16(af, bf, ov[dt], 0, 0, 0);
    }
  }

#pragma unroll
  for (int dt = 0; dt < 4; dt++)
#pragma unroll
    for (int i = 0; i < 4; i++) {
      int grow = m0 + quad * 4 + i;
      O[((size_t)bb * S + grow) * 512 + h * 64 + dt * 16 + mfm] = f2bf(ov[dt][i]);
    }
}

__global__ __launch_bounds__(256) void zero_f32(float* __restrict__ p, int n) {
  int i = blockIdx.x * 256 + threadIdx.x;
  if (i < n) p[i] = 0.f;
}

// ---------------------------------------------------------------
// head GEMM (per row-chunk): Z[rows,96] += A[rows,32768] @ Bt[96,32768]^T
// grid (rows/64 m-tiles, 32 k-chunks of 1024), block 256 = 4 waves
// ---------------------------------------------------------------
__global__ __launch_bounds__(256) void head_gemm(const u16* __restrict__ A,
                                                 const u16* __restrict__ Bt,
                                                 float* __restrict__ Z) {
  __shared__ u16 lA[64 * 32];
  __shared__ u16 lB[96 * 32];
  int tid = threadIdx.x, lane = tid & 63, w = tid >> 6;
  int m0 = blockIdx.x * 64;
  int kbase = blockIdx.y * 1024;
  const int mfm = lane & 15, mfk = (lane >> 4) * 8;
  f32x4 acc[6] = {};

  for (int kk = 0; kk < 1024; kk += 32) {
    int k0 = kbase + kk;
    uint4 a0 = *(const uint4*)(A + (size_t)(m0 + (tid >> 2)) * 32768 + k0 + (tid & 3) * 8);
    uint4 b0 = *(const uint4*)(Bt + (size_t)(tid >> 2) * 32768 + k0 + (tid & 3) * 8);
    uint4 b1;
    bool has2 = tid < 128;
    int slot2 = 256 + tid, row2 = slot2 >> 2, c82 = (slot2 & 3) * 8;
    if (has2) b1 = *(const uint4*)(Bt + (size_t)row2 * 32768 + k0 + c82);
    __syncthreads();
    *(uint4*)(lA + (tid >> 2) * 32 + (tid & 3) * 8) = a0;
    *(uint4*)(lB + (tid >> 2) * 32 + (tid & 3) * 8) = b0;
    if (has2) *(uint4*)(lB + row2 * 32 + c82) = b1;
    __syncthreads();
    short8 af = *(const short8*)(lA + (w * 16 + mfm) * 32 + mfk);
#pragma unroll
    for (int nt = 0; nt < 6; nt++) {
      short8 bfr = *(const short8*)(lB + (nt * 16 + mfm) * 32 + mfk);
      acc[nt] = __builtin_amdgcn_mfma_f32_16x16x32_bf16(af, bfr, acc[nt], 0, 0, 0);
    }
  }
  int cr = (lane >> 4) * 4, cc = lane & 15;
#pragma unroll
  for (int nt = 0; nt < 6; nt++)
#pragma unroll
    for (int i = 0; i < 4; i++)
      atomicAdd(&Z[(size_t)(m0 + w * 16 + cr + i) * NPRED + nt * 16 + cc], acc[nt][i]);
}

// out[b,t,v] = (Z[b*32+v, t] + head_b[t]) * stdev[b,v] + mean[b,v]
__global__ __launch_bounds__(256) void final_kernel(const float* __restrict__ Z,
                                                    const float* __restrict__ head_b,
                                                    const float* __restrict__ meanb,
                                                    const float* __restrict__ stdevb,
                                                    float* __restrict__ out) {
  int idx = blockIdx.x * 256 + threadIdx.x;
  if (idx >= NBS * NPRED * NNV) return;
  int v = idx & 31;
  int t = (idx >> 5) % NPRED;
  int b = idx / (NPRED * NNV);
  int bv = b * 32 + v;
  out[idx] = (Z[(size_t)bv * NPRED + t] + head_b[t]) * stdevb[bv] + meanb[bv];
}

// ---------------------------------------------------------------
extern "C" void kernel_launch(void* const* d_in, const int* in_sizes, int n_in,
                              void* d_out, int out_size, void* d_ws, size_t ws_size,
                              hipStream_t stream) {
  const float* tokens = (const float*)d_in[0];
  const float* pe_w   = (const float*)d_in[1];
  const float* pe_b   = (const float*)d_in[2];
  const float* norm_w = (const float*)d_in[3];
  const float* head_w = (const float*)d_in[4];
  const float* head_b = (const float*)d_in[5];
  const float* wq[2] = {(const float*)d_in[6],  (const float*)d_in[15]};
  const float* wk[2] = {(const float*)d_in[7],  (const float*)d_in[16]};
  const float* wv[2] = {(const float*)d_in[8],  (const float*)d_in[17]};
  const float* wo[2] = {(const float*)d_in[9],  (const float*)d_in[18]};
  const float* w1[2] = {(const float*)d_in[10], (const float*)d_in[19]};
  const float* w2[2] = {(const float*)d_in[11], (const float*)d_in[20]};
  const float* w3[2] = {(const float*)d_in[12], (const float*)d_in[21]};
  const float* an[2] = {(const float*)d_in[13], (const float*)d_in[22]};
  const float* fn[2] = {(const float*)d_in[14], (const float*)d_in[23]};

  char* ws = (char*)d_ws;
  size_t off = 0;
  auto alloc = [&](size_t bytes) -> void* {
    void* p = ws + off;
    off += (bytes + 255) & ~(size_t)255;
    return p;
  };
  // ~215 MB total workspace
  float* meanb  = (float*)alloc(1024 * 4);
  float* invstd = (float*)alloc(1024 * 4);
  float* stdevb = (float*)alloc(1024 * 4);
  u16* wl_qkv = (u16*)alloc((size_t)1536 * 512 * 2);    // current layer only
  u16* wl_o   = (u16*)alloc((size_t)512 * 512 * 2);
  u16* wl_13  = (u16*)alloc((size_t)3072 * 512 * 2);    // W1/W3 column-interleaved
  u16* wl_2   = (u16*)alloc((size_t)512 * 1536 * 2);
  u16* hw_t   = (u16*)alloc((size_t)96 * 32768 * 2);
  float* z    = (float*)alloc((size_t)1024 * 96 * 4);
  float* h    = (float*)alloc((size_t)MROWS * ND * 4);          // 134 MB residual
  u16* xn     = (u16*)alloc((size_t)RCHUNK * ND * 2);           // 16.8 MB (rmsnorm out / attn out)
  u16* g1     = (u16*)alloc((size_t)RCHUNK * NHID * 2);         // 50.3 MB
  float* bounce = (float*)g1;   // 8*2048*512*4 = 33.5 MB, overlays dead g1

  stats_kernel<<<1024, 256, 0, stream>>>(tokens, meanb, invstd, stdevb);
  convt_kernel<<<dim3(1024, 3), 256, 0, stream>>>(head_w, hw_t, 32768, 96, 0, 1);
  patch_embed<<<2048, 256, 0, stream>>>(tokens, pe_w, pe_b, meanb, invstd, h);

  for (int l = 0; l < 8; l++) {
    int ph = l >> 2, li = l & 3;
    // convert this layer's weights to bf16 transposed (N x K)
    convt_kernel<<<dim3(16, 16), 256, 0, stream>>>(wq[ph] + (size_t)li * 512 * 512, wl_qkv, 512, 512, 0, 1);
    convt_kernel<<<dim3(16, 16), 256, 0, stream>>>(wk[ph] + (size_t)li * 512 * 512, wl_qkv, 512, 512, 512, 1);
    convt_kernel<<<dim3(16, 16), 256, 0, stream>>>(wv[ph] + (size_t)li * 512 * 512, wl_qkv, 512, 512, 1024, 1);
    convt_kernel<<<dim3(16, 16), 256, 0, stream>>>(wo[ph] + (size_t)li * 512 * 512, wl_o, 512, 512, 0, 1);
    convt_kernel<<<dim3(16, 48), 256, 0, stream>>>(w1[ph] + (size_t)li * 512 * 1536, wl_13, 512, 1536, 0, 2);
    convt_kernel<<<dim3(16, 48), 256, 0, stream>>>(w3[ph] + (size_t)li * 512 * 1536, wl_13, 512, 1536, 1, 2);
    convt_kernel<<<dim3(48, 16), 256, 0, stream>>>(w2[ph] + (size_t)li * 1536 * 512, wl_2, 1536, 512, 0, 1);
    const float* anl = an[ph] + li * 512;
    const float* fnl = fn[ph] + li * 512;

    for (int c = 0; c < NCHUNK; c++) {
      float* hc = h + (size_t)c * RCHUNK * ND;
      rmsnorm_bf16<<<RCHUNK / 4, 256, 0, stream>>>(hc, anl, xn);
      gemm_bt<0><<<dim3(12, RCHUNK / 128), 256, 0, stream>>>(xn, wl_qkv, g1, (float*)nullptr, 1536, 512, 1536);
      // attention output overlays xn (dead after qkv GEMM)
      if (ph == 0) attn_mfma<32, false><<<dim3(8, RCHUNK / 32), 128, 0, stream>>>(g1, xn);
      else         attn_mfma<64, true ><<<dim3(8, RCHUNK / 64), 256, 0, stream>>>(g1, xn);
      gemm_bt<1><<<dim3(4, RCHUNK / 128), 256, 0, stream>>>(xn, wl_o, (u16*)nullptr, hc, 512, 512, 512);
      rmsnorm_bf16<<<RCHUNK / 4, 256, 0, stream>>>(hc, fnl, xn);
      // fused W1|W3 (column-interleaved) + SwiGLU epilogue -> g1 (M x 1536)
      gemm_bt<3><<<dim3(24, RCHUNK / 128), 256, 0, stream>>>(xn, wl_13, g1, (float*)nullptr, 3072, 512, 1536);
      gemm_bt<1><<<dim3(4, RCHUNK / 128), 256, 0, stream>>>(g1, wl_2, (u16*)nullptr, hc, 512, 1536, 512);
    }

    if (l == 3) {
      // rel->enc handoff: rms_norm + within-batch (p,v)->(v,p) row permute,
      // 8 batches per round through the 33.5 MB bounce (g1 space is dead)
      for (int g = 0; g < 4; g++) {
        float* hg = h + (size_t)g * 8 * 2048 * ND;
        rms_transpose_batch<<<dim3(512, 8), 256, 0, stream>>>(hg, norm_w, bounce);
        copy_f32v4<<<8192, 256, 0, stream>>>((const float4*)bounce, (float4*)hg, 8 * 2048 * ND / 4);
      }
    }
  }

  // head: per-chunk rmsnorm -> 256 complete M-rows of the 1024x96x32768 GEMM
  zero_f32<<<384, 256, 0, stream>>>(z, 1024 * 96);
  for (int c = 0; c < NCHUNK; c++) {
    rmsnorm_bf16<<<RCHUNK / 4, 256, 0, stream>>>(h + (size_t)c * RCHUNK * ND, norm_w, xn);
    head_gemm<<<dim3(RCHUNK / 64 / 64, 32), 256, 0, stream>>>(xn, hw_t, z + (size_t)c * (RCHUNK / 64) * NPRED);
  }
  final_kernel<<<384, 256, 0, stream>>>(z, head_b, meanb, stdevb, (float*)d_out);
}

// Round 6
// 7962.273 us; speedup vs baseline: 1.8248x; 1.0971x over previous
//
#include <hip/hip_runtime.h>

using u16 = unsigned short;
typedef float f32x4 __attribute__((ext_vector_type(4)));
typedef short short8 __attribute__((ext_vector_type(8)));

// ---------- bf16 helpers (buffers held as u16; RNE conversion) ----------
__device__ __forceinline__ float bf2f(u16 u) {
  return __uint_as_float(((unsigned)u) << 16);
}
__device__ __forceinline__ u16 f2bf(float f) {
  unsigned u = __float_as_uint(f);
  unsigned r = u + 0x7fffu + ((u >> 16) & 1u);
  return (u16)(r >> 16);
}

// async global->LDS, 16B per lane; LDS dest is wave-uniform base + lane*16
__device__ __forceinline__ void gload16(const void* g, void* l) {
  __builtin_amdgcn_global_load_lds(
      reinterpret_cast<const __attribute__((address_space(1))) unsigned int*>(
          reinterpret_cast<uintptr_t>(g)),
      reinterpret_cast<__attribute__((address_space(3))) unsigned int*>(
          reinterpret_cast<uintptr_t>(l)),
      16, 0, 0);
}

// model constants
#define NBS 32
#define NSEQ 512
#define NNV 32
#define ND 512
#define NHID 1536
#define NPNUM 64
#define NPRED 96
#define MROWS 65536           // tokens per phase
#define RCHUNK 16384          // row chunk (multiple of 64)
#define NCHUNK (MROWS / RCHUNK)

// ---------------------------------------------------------------
// per-(b,v) mean / stdev over SEQ
// ---------------------------------------------------------------
__global__ __launch_bounds__(256) void stats_kernel(const float* __restrict__ tokens,
                                                    float* __restrict__ meanb,
                                                    float* __restrict__ invstd,
                                                    float* __restrict__ stdevb) {
  int bv = blockIdx.x;            // 0..1023
  int b = bv >> 5, v = bv & 31;
  int tid = threadIdx.x;
  float s = 0.f, s2 = 0.f;
  for (int t = tid; t < NSEQ; t += 256) {
    float x = tokens[((size_t)b * NSEQ + t) * NNV + v];
    s += x; s2 += x * x;
  }
  __shared__ float rs[256], rs2[256];
  rs[tid] = s; rs2[tid] = s2;
  __syncthreads();
  for (int o = 128; o; o >>= 1) {
    if (tid < o) { rs[tid] += rs[tid + o]; rs2[tid] += rs2[tid + o]; }
    __syncthreads();
  }
  if (tid == 0) {
    float m = rs[0] / (float)NSEQ;
    float var = rs2[0] / (float)NSEQ - m * m;
    float sd = sqrtf(var + 1e-5f);
    meanb[bv] = m;
    stdevb[bv] = sd;
    invstd[bv] = 1.f / sd;
  }
}

// ---------------------------------------------------------------
// weight convert + transpose: src f32 (K, N) -> bf16 row n, col k at dst.
// generic single-matrix version (head weight).
// grid (K/32, N/32), block 256
// ---------------------------------------------------------------
__global__ __launch_bounds__(256) void convt_kernel(const float* __restrict__ S,
                                                    u16* __restrict__ D,
                                                    int K, int N) {
  __shared__ float t[32][33];
  int k0 = blockIdx.x * 32, n0 = blockIdx.y * 32;
  int tx = threadIdx.x & 31, ty = threadIdx.x >> 5;    // ty 0..7
  for (int r = ty; r < 32; r += 8) t[r][tx] = S[(size_t)(k0 + r) * N + n0 + tx];
  __syncthreads();
  for (int r = ty; r < 32; r += 8)
    D[(size_t)(n0 + r) * K + k0 + tx] = f2bf(t[tx][r]);
}

// 4 independent 512x512 transposes in one launch (z selects matrix)
__global__ __launch_bounds__(256) void convt4_kernel(const float* __restrict__ S0,
                                                     const float* __restrict__ S1,
                                                     const float* __restrict__ S2,
                                                     const float* __restrict__ S3,
                                                     u16* __restrict__ D0,
                                                     u16* __restrict__ D1,
                                                     u16* __restrict__ D2,
                                                     u16* __restrict__ D3) {
  __shared__ float t[32][33];
  const float* S = blockIdx.z == 0 ? S0 : blockIdx.z == 1 ? S1 : blockIdx.z == 2 ? S2 : S3;
  u16* D = blockIdx.z == 0 ? D0 : blockIdx.z == 1 ? D1 : blockIdx.z == 2 ? D2 : D3;
  int k0 = blockIdx.x * 32, n0 = blockIdx.y * 32;
  int tx = threadIdx.x & 31, ty = threadIdx.x >> 5;
  for (int r = ty; r < 32; r += 8) t[r][tx] = S[(size_t)(k0 + r) * 512 + n0 + tx];
  __syncthreads();
  for (int r = ty; r < 32; r += 8)
    D[(size_t)(n0 + r) * 512 + k0 + tx] = f2bf(t[tx][r]);
}

// 2-source column-interleaved transpose (SwiGLU W1|W3): dst row = n*2 + z
// grid (K/32, N/32, 2)
__global__ __launch_bounds__(256) void convt2i_kernel(const float* __restrict__ S0,
                                                      const float* __restrict__ S1,
                                                      u16* __restrict__ D,
                                                      int K, int N) {
  __shared__ float t[32][33];
  const float* S = blockIdx.z == 0 ? S0 : S1;
  int k0 = blockIdx.x * 32, n0 = blockIdx.y * 32;
  int tx = threadIdx.x & 31, ty = threadIdx.x >> 5;
  for (int r = ty; r < 32; r += 8) t[r][tx] = S[(size_t)(k0 + r) * N + n0 + tx];
  __syncthreads();
  for (int r = ty; r < 32; r += 8)
    D[(size_t)((n0 + r) * 2 + blockIdx.z) * K + k0 + tx] = f2bf(t[tx][r]);
}

// ---------------------------------------------------------------
// patch embed: one block per (b,p); 32 output rows (v) of 512.
// ---------------------------------------------------------------
__global__ __launch_bounds__(256) void patch_embed(const float* __restrict__ tokens,
                                                   const float* __restrict__ pe_w,
                                                   const float* __restrict__ pe_b,
                                                   const float* __restrict__ meanb,
                                                   const float* __restrict__ invstd,
                                                   float* __restrict__ H) {
  __shared__ float pw[16 * ND];
  __shared__ float pv[32][16];
  int bp = blockIdx.x;                 // b*64+p
  int b = bp >> 6, p = bp & 63;
  int tid = threadIdx.x;
  for (int i = tid; i < 16 * ND; i += 256) pw[i] = pe_w[i];
  for (int idx = tid; idx < 512; idx += 256) {
    int v = idx >> 4, j = idx & 15;
    int t = p * 8 + j;
    if (t > NSEQ - 1) t = NSEQ - 1;    // repeat-last padding
    int bv = b * 32 + v;
    pv[v][j] = (tokens[((size_t)b * NSEQ + t) * NNV + v] - meanb[bv]) * invstd[bv];
  }
  __syncthreads();
  for (int o = tid; o < 32 * ND; o += 256) {
    int v = o >> 9, d = o & 511;
    float acc = pe_b[d];
#pragma unroll
    for (int j = 0; j < 16; j++) acc += pv[v][j] * pw[j * ND + d];
    H[((size_t)bp * 32 + v) * ND + d] = acc;
  }
}

// ---------------------------------------------------------------
// rmsnorm: fp32 rows (x 512) -> bf16 out, 1 wave per row
// ---------------------------------------------------------------
__global__ __launch_bounds__(256) void rmsnorm_bf16(const float* __restrict__ X,
                                                    const float* __restrict__ W,
                                                    u16* __restrict__ Y) {
  int wave = threadIdx.x >> 6, lane = threadIdx.x & 63;
  size_t row = (size_t)blockIdx.x * 4 + wave;
  const float4* xr = (const float4*)(X + row * ND);
  float4 a = xr[lane], b = xr[64 + lane];
  float s = a.x*a.x + a.y*a.y + a.z*a.z + a.w*a.w
          + b.x*b.x + b.y*b.y + b.z*b.z + b.w*b.w;
  for (int o = 1; o < 64; o <<= 1) s += __shfl_xor(s, o);
  float sc = rsqrtf(s * (1.f / ND) + 1e-5f);
  const float4* wr = (const float4*)W;
  float4 wa = wr[lane], wb = wr[64 + lane];
  ushort4 pa, pb;
  pa.x = f2bf(a.x * sc * wa.x); pa.y = f2bf(a.y * sc * wa.y);
  pa.z = f2bf(a.z * sc * wa.z); pa.w = f2bf(a.w * sc * wa.w);
  pb.x = f2bf(b.x * sc * wb.x); pb.y = f2bf(b.y * sc * wb.y);
  pb.z = f2bf(b.z * sc * wb.z); pb.w = f2bf(b.w * sc * wb.w);
  ushort4* yr = (ushort4*)(Y + row * ND);
  yr[lane] = pa; yr[64 + lane] = pb;
}

// rmsnorm + within-batch row permute (p,v)->(v,p), fp32 out to bounce.
// grid (512, GB); batch bb = blockIdx.y
__global__ __launch_bounds__(256) void rms_transpose_batch(const float* __restrict__ X,
                                                           const float* __restrict__ W,
                                                           float* __restrict__ Y) {
  int bb = blockIdx.y;
  X += (size_t)bb * 2048 * ND;
  Y += (size_t)bb * 2048 * ND;
  int wave = threadIdx.x >> 6, lane = threadIdx.x & 63;
  int row = blockIdx.x * 4 + wave;               // 0..2047 = p*32+v
  int p = row >> 5, v = row & 31;
  size_t r2 = (size_t)v * 64 + p;                // v*64+p
  const float4* xr = (const float4*)(X + (size_t)row * ND);
  float4 a = xr[lane], b4 = xr[64 + lane];
  float s = a.x*a.x + a.y*a.y + a.z*a.z + a.w*a.w
          + b4.x*b4.x + b4.y*b4.y + b4.z*b4.z + b4.w*b4.w;
  for (int o = 1; o < 64; o <<= 1) s += __shfl_xor(s, o);
  float sc = rsqrtf(s * (1.f / ND) + 1e-5f);
  const float4* wr = (const float4*)W;
  float4 wa = wr[lane], wb = wr[64 + lane];
  float4 oa, ob;
  oa.x = a.x * sc * wa.x;  oa.y = a.y * sc * wa.y;
  oa.z = a.z * sc * wa.z;  oa.w = a.w * sc * wa.w;
  ob.x = b4.x * sc * wb.x; ob.y = b4.y * sc * wb.y;
  ob.z = b4.z * sc * wb.z; ob.w = b4.w * sc * wb.w;
  float4* yr = (float4*)(Y + r2 * ND);
  yr[lane] = oa; yr[64 + lane] = ob;
}

__global__ __launch_bounds__(256) void copy_f32v4(const float4* __restrict__ S,
                                                  float4* __restrict__ D, int n) {
  int i = blockIdx.x * 256 + threadIdx.x;
  if (i < n) D[i] = S[i];
}

// ---------------------------------------------------------------
// MFMA GEMM: C[M,N] = A[M,K] @ Bt[N,K]^T ; A,Bt bf16(u16), acc fp32.
// MODE 0: store bf16 into Cb (width NOUT==N).
// MODE 1: Hres[M,N] += result (fp32 residual).
// MODE 3: SwiGLU-interleaved: even col=u (W1), odd col=g (W3);
//         even lanes store silu(u)*g at col/2 into Cb (width NOUT==N/2).
// block 256 = 4 waves (2x2 of 64x64), tile 128x128, K per barrier = 64.
// __launch_bounds__(256,4): cap VGPR at 128 -> 4 blocks/CU so barrier
// drains overlap with a 4th resident block (live set ~115 VGPR, fits).
// grid (N/128, M/128); K % 64 == 0.
// ---------------------------------------------------------------
template<int MODE>
__global__ __launch_bounds__(256, 4) void gemm_bt(const u16* __restrict__ A,
                                                  const u16* __restrict__ Bt,
                                                  u16* __restrict__ Cb,
                                                  float* __restrict__ Hres,
                                                  int N, int K, int NOUT) {
  __shared__ u16 lA[2][128 * 32];
  __shared__ u16 lB[2][128 * 32];
  const int tid = threadIdx.x;
  const int lane = tid & 63;
  const int w = tid >> 6;
  const int wm = (w >> 1) * 64, wn = (w & 1) * 64;
  const int m0 = blockIdx.y * 128, n0 = blockIdx.x * 128;
  const int rowL = tid >> 2;            // 0..63
  const int colL = (tid & 3) * 8;       // k element offset within a 32-half
  const int mfm = lane & 15, mfk = (lane >> 4) * 8;

  const u16* pA0 = A + (size_t)(m0 + rowL) * K + colL;
  const u16* pA1 = pA0 + (size_t)64 * K;
  const u16* pB0 = Bt + (size_t)(n0 + rowL) * K + colL;
  const u16* pB1 = pB0 + (size_t)64 * K;

  f32x4 acc[4][4] = {};

  for (int k0 = 0; k0 < K; k0 += 64) {
    __syncthreads();                    // prev iter's LDS reads done
#pragma unroll
    for (int hh = 0; hh < 2; hh++) {
      int kk = k0 + hh * 32;
      gload16(pA0 + kk, lA[hh] + w * 512);
      gload16(pA1 + kk, lA[hh] + 2048 + w * 512);
      gload16(pB0 + kk, lB[hh] + w * 512);
      gload16(pB1 + kk, lB[hh] + 2048 + w * 512);
    }
    __syncthreads();                    // staging complete (vmcnt drained)
#pragma unroll
    for (int hh = 0; hh < 2; hh++) {
      short8 af[4], bfr[4];
#pragma unroll
      for (int i = 0; i < 4; i++) {
        af[i]  = *(const short8*)(lA[hh] + (wm + i * 16 + mfm) * 32 + mfk);
        bfr[i] = *(const short8*)(lB[hh] + (wn + i * 16 + mfm) * 32 + mfk);
      }
#pragma unroll
      for (int mi = 0; mi < 4; mi++)
#pragma unroll
        for (int ni = 0; ni < 4; ni++)
          acc[mi][ni] = __builtin_amdgcn_mfma_f32_16x16x32_bf16(af[mi], bfr[ni], acc[mi][ni], 0, 0, 0);
    }
  }

  const int cr = (lane >> 4) * 4, cc = lane & 15;
#pragma unroll
  for (int mi = 0; mi < 4; mi++) {
#pragma unroll
    for (int ni = 0; ni < 4; ni++) {
#pragma unroll
      for (int i = 0; i < 4; i++) {
        int r = m0 + wm + mi * 16 + cr + i;
        int c = n0 + wn + ni * 16 + cc;
        if (MODE == 1) {
          Hres[(size_t)r * N + c] += acc[mi][ni][i];
        } else if (MODE == 3) {
          float mine = acc[mi][ni][i];
          float other = __shfl_xor(mine, 1);
          if ((lane & 1) == 0) {        // even lane holds u (W1), partner g (W3)
            float u = mine;
            Cb[(size_t)r * NOUT + (c >> 1)] = f2bf(u / (1.f + __expf(-u)) * other);
          }
        } else {
          Cb[(size_t)r * NOUT + c] = f2bf(acc[mi][ni][i]);
        }
      }
    }
  }
}

// ---------------------------------------------------------------
// MFMA attention: one block per (head, group). QKV rows 1536 wide [q|k|v],
// head slice 64. S=32 (rel): 2 waves; S=64 (enc: rope+causal): 4 waves.
// ---------------------------------------------------------------
template<int S, bool ROPE>
__global__ __launch_bounds__(64 * (S / 16)) void attn_mfma(const u16* __restrict__ QKV,
                                                           u16* __restrict__ O) {
  constexpr int WAVES = S / 16;
  constexpr int NT = S / 16;          // score col tiles
  constexpr int LDW = 68;             // padded LDS row stride (u16)
  constexpr int T = 64 * WAVES;
  __shared__ u16 qs[S * LDW];
  __shared__ u16 ks[S * LDW];
  __shared__ u16 vt[64 * LDW];        // vt[d][j] = V[j][d]
  __shared__ u16 pbuf[S * LDW];
  int h = blockIdx.x, bb = blockIdx.y, tid = threadIdx.x;
  const int lane = tid & 63, w = tid >> 6;
  const int mfm = lane & 15, quad = lane >> 4;
  const int m0 = w * 16;
  size_t base = ((size_t)bb * S) * 1536 + h * 64;

  // load q,k (rope applied in fp32), v transposed
  for (int idx = tid; idx < S * 16; idx += T) {
    int s = idx >> 4, c4 = (idx & 15) * 4;
    const u16* rowp = QKV + base + (size_t)s * 1536;
    ushort4 qv = *(const ushort4*)(rowp + c4);
    ushort4 kv = *(const ushort4*)(rowp + 512 + c4);
    if (ROPE) {
      int i0 = c4 >> 1;               // rope pair indices i0, i0+1
      float inv0 = powf(10000.f, -(float)i0 * (1.f / 32.f));
      float inv1 = powf(10000.f, -(float)(i0 + 1) * (1.f / 32.f));
      float sn0, cn0, sn1, cn1;
      sincosf((float)s * inv0, &sn0, &cn0);
      sincosf((float)s * inv1, &sn1, &cn1);
      float q0 = bf2f(qv.x), q1 = bf2f(qv.y), q2 = bf2f(qv.z), q3 = bf2f(qv.w);
      float k0 = bf2f(kv.x), k1 = bf2f(kv.y), k2 = bf2f(kv.z), k3 = bf2f(kv.w);
      qv.x = f2bf(q0 * cn0 - q1 * sn0); qv.y = f2bf(q0 * sn0 + q1 * cn0);
      qv.z = f2bf(q2 * cn1 - q3 * sn1); qv.w = f2bf(q2 * sn1 + q3 * cn1);
      kv.x = f2bf(k0 * cn0 - k1 * sn0); kv.y = f2bf(k0 * sn0 + k1 * cn0);
      kv.z = f2bf(k2 * cn1 - k3 * sn1); kv.w = f2bf(k2 * sn1 + k3 * cn1);
    }
    *(ushort4*)(qs + s * LDW + c4) = qv;
    *(ushort4*)(ks + s * LDW + c4) = kv;
    ushort4 vv = *(const ushort4*)(rowp + 1024 + c4);
    vt[(c4 + 0) * LDW + s] = vv.x;
    vt[(c4 + 1) * LDW + s] = vv.y;
    vt[(c4 + 2) * LDW + s] = vv.z;
    vt[(c4 + 3) * LDW + s] = vv.w;
  }
  __syncthreads();

  // scores: sc[nt] = Q[m0..m0+15,:] @ K[nt*16..,:]^T  (K-dim = 64)
  f32x4 sc[NT] = {};
#pragma unroll
  for (int half = 0; half < 64; half += 32) {
    short8 af = *(const short8*)(qs + (m0 + mfm) * LDW + half + quad * 8);
#pragma unroll
    for (int nt = 0; nt < NT; nt++) {
      short8 bf = *(const short8*)(ks + (nt * 16 + mfm) * LDW + half + quad * 8);
      sc[nt] = __builtin_amdgcn_mfma_f32_16x16x32_bf16(af, bf, sc[nt], 0, 0, 0);
    }
  }

  // in-register softmax: row r = m0+quad*4+i; its 64 cols = 16 quad-lanes x NT accs
#pragma unroll
  for (int i = 0; i < 4; i++) {
    int grow = m0 + quad * 4 + i;
    float mx = -1e30f;
#pragma unroll
    for (int nt = 0; nt < NT; nt++) {
      float v = sc[nt][i] * 0.125f;                      // 1/sqrt(64)
      if (ROPE && (nt * 16 + mfm) > grow) v = -1e30f;    // causal
      sc[nt][i] = v;
      mx = fmaxf(mx, v);
    }
#pragma unroll
    for (int o = 1; o < 16; o <<= 1) mx = fmaxf(mx, __shfl_xor(mx, o));
    float sum = 0.f;
#pragma unroll
    for (int nt = 0; nt < NT; nt++) {
      float e = __expf(sc[nt][i] - mx);
      sc[nt][i] = e;
      sum += e;
    }
#pragma unroll
    for (int o = 1; o < 16; o <<= 1) sum += __shfl_xor(sum, o);
    float r = 1.f / sum;
#pragma unroll
    for (int nt = 0; nt < NT; nt++)
      pbuf[grow * LDW + nt * 16 + mfm] = f2bf(sc[nt][i] * r);
  }
  // PV uses only this wave's own P rows (m0..m0+15) -> no barrier needed.

  f32x4 ov[4] = {};
#pragma unroll
  for (int half = 0; half < S; half += 32) {
    short8 af = *(const short8*)(pbuf + (m0 + mfm) * LDW + half + quad * 8);
#pragma unroll
    for (int dt = 0; dt < 4; dt++) {
      short8 bf = *(const short8*)(vt + (dt * 16 + mfm) * LDW + half + quad * 8);
      ov[dt] = __builtin_amdgcn_mfma_f32_16x16x32_bf16(af, bf, ov[dt], 0, 0, 0);
    }
  }

#pragma unroll
  for (int dt = 0; dt < 4; dt++)
#pragma unroll
    for (int i = 0; i < 4; i++) {
      int grow = m0 + quad * 4 + i;
      O[((size_t)bb * S + grow) * 512 + h * 64 + dt * 16 + mfm] = f2bf(ov[dt][i]);
    }
}

__global__ __launch_bounds__(256) void zero_f32(float* __restrict__ p, int n) {
  int i = blockIdx.x * 256 + threadIdx.x;
  if (i < n) p[i] = 0.f;
}

// ---------------------------------------------------------------
// head GEMM (per row-chunk): Z[rows,96] += A[rows,32768] @ Bt[96,32768]^T
// grid (rows/64 m-tiles, 32 k-chunks of 1024), block 256 = 4 waves
// ---------------------------------------------------------------
__global__ __launch_bounds__(256) void head_gemm(const u16* __restrict__ A,
                                                 const u16* __restrict__ Bt,
                                                 float* __restrict__ Z) {
  __shared__ u16 lA[64 * 32];
  __shared__ u16 lB[96 * 32];
  int tid = threadIdx.x, lane = tid & 63, w = tid >> 6;
  int m0 = blockIdx.x * 64;
  int kbase = blockIdx.y * 1024;
  const int mfm = lane & 15, mfk = (lane >> 4) * 8;
  f32x4 acc[6] = {};

  for (int kk = 0; kk < 1024; kk += 32) {
    int k0 = kbase + kk;
    uint4 a0 = *(const uint4*)(A + (size_t)(m0 + (tid >> 2)) * 32768 + k0 + (tid & 3) * 8);
    uint4 b0 = *(const uint4*)(Bt + (size_t)(tid >> 2) * 32768 + k0 + (tid & 3) * 8);
    uint4 b1;
    bool has2 = tid < 128;
    int slot2 = 256 + tid, row2 = slot2 >> 2, c82 = (slot2 & 3) * 8;
    if (has2) b1 = *(const uint4*)(Bt + (size_t)row2 * 32768 + k0 + c82);
    __syncthreads();
    *(uint4*)(lA + (tid >> 2) * 32 + (tid & 3) * 8) = a0;
    *(uint4*)(lB + (tid >> 2) * 32 + (tid & 3) * 8) = b0;
    if (has2) *(uint4*)(lB + row2 * 32 + c82) = b1;
    __syncthreads();
    short8 af = *(const short8*)(lA + (w * 16 + mfm) * 32 + mfk);
#pragma unroll
    for (int nt = 0; nt < 6; nt++) {
      short8 bfr = *(const short8*)(lB + (nt * 16 + mfm) * 32 + mfk);
      acc[nt] = __builtin_amdgcn_mfma_f32_16x16x32_bf16(af, bfr, acc[nt], 0, 0, 0);
    }
  }
  int cr = (lane >> 4) * 4, cc = lane & 15;
#pragma unroll
  for (int nt = 0; nt < 6; nt++)
#pragma unroll
    for (int i = 0; i < 4; i++)
      atomicAdd(&Z[(size_t)(m0 + w * 16 + cr + i) * NPRED + nt * 16 + cc], acc[nt][i]);
}

// out[b,t,v] = (Z[b*32+v, t] + head_b[t]) * stdev[b,v] + mean[b,v]
__global__ __launch_bounds__(256) void final_kernel(const float* __restrict__ Z,
                                                    const float* __restrict__ head_b,
                                                    const float* __restrict__ meanb,
                                                    const float* __restrict__ stdevb,
                                                    float* __restrict__ out) {
  int idx = blockIdx.x * 256 + threadIdx.x;
  if (idx >= NBS * NPRED * NNV) return;
  int v = idx & 31;
  int t = (idx >> 5) % NPRED;
  int b = idx / (NPRED * NNV);
  int bv = b * 32 + v;
  out[idx] = (Z[(size_t)bv * NPRED + t] + head_b[t]) * stdevb[bv] + meanb[bv];
}

// ---------------------------------------------------------------
extern "C" void kernel_launch(void* const* d_in, const int* in_sizes, int n_in,
                              void* d_out, int out_size, void* d_ws, size_t ws_size,
                              hipStream_t stream) {
  const float* tokens = (const float*)d_in[0];
  const float* pe_w   = (const float*)d_in[1];
  const float* pe_b   = (const float*)d_in[2];
  const float* norm_w = (const float*)d_in[3];
  const float* head_w = (const float*)d_in[4];
  const float* head_b = (const float*)d_in[5];
  const float* wq[2] = {(const float*)d_in[6],  (const float*)d_in[15]};
  const float* wk[2] = {(const float*)d_in[7],  (const float*)d_in[16]};
  const float* wv[2] = {(const float*)d_in[8],  (const float*)d_in[17]};
  const float* wo[2] = {(const float*)d_in[9],  (const float*)d_in[18]};
  const float* w1[2] = {(const float*)d_in[10], (const float*)d_in[19]};
  const float* w2[2] = {(const float*)d_in[11], (const float*)d_in[20]};
  const float* w3[2] = {(const float*)d_in[12], (const float*)d_in[21]};
  const float* an[2] = {(const float*)d_in[13], (const float*)d_in[22]};
  const float* fn[2] = {(const float*)d_in[14], (const float*)d_in[23]};

  char* ws = (char*)d_ws;
  size_t off = 0;
  auto alloc = [&](size_t bytes) -> void* {
    void* p = ws + off;
    off += (bytes + 255) & ~(size_t)255;
    return p;
  };
  // ~215 MB total workspace
  float* meanb  = (float*)alloc(1024 * 4);
  float* invstd = (float*)alloc(1024 * 4);
  float* stdevb = (float*)alloc(1024 * 4);
  u16* wl_qkv = (u16*)alloc((size_t)1536 * 512 * 2);    // current layer only
  u16* wl_o   = (u16*)alloc((size_t)512 * 512 * 2);
  u16* wl_13  = (u16*)alloc((size_t)3072 * 512 * 2);    // W1/W3 column-interleaved
  u16* wl_2   = (u16*)alloc((size_t)512 * 1536 * 2);
  u16* hw_t   = (u16*)alloc((size_t)96 * 32768 * 2);
  float* z    = (float*)alloc((size_t)1024 * 96 * 4);
  float* h    = (float*)alloc((size_t)MROWS * ND * 4);          // 134 MB residual
  u16* xn     = (u16*)alloc((size_t)RCHUNK * ND * 2);           // 16.8 MB (rmsnorm out / attn out)
  u16* g1     = (u16*)alloc((size_t)RCHUNK * NHID * 2);         // 50.3 MB
  float* bounce = (float*)g1;   // 8*2048*512*4 = 33.5 MB, overlays dead g1

  stats_kernel<<<1024, 256, 0, stream>>>(tokens, meanb, invstd, stdevb);
  convt_kernel<<<dim3(1024, 3), 256, 0, stream>>>(head_w, hw_t, 32768, 96);
  patch_embed<<<2048, 256, 0, stream>>>(tokens, pe_w, pe_b, meanb, invstd, h);

  for (int l = 0; l < 8; l++) {
    int ph = l >> 2, li = l & 3;
    size_t wo512 = (size_t)li * 512 * 512;
    size_t wo1536 = (size_t)li * 512 * 1536;
    // convert this layer's weights to bf16 transposed (N x K), 3 launches
    convt4_kernel<<<dim3(16, 16, 4), 256, 0, stream>>>(
        wq[ph] + wo512, wk[ph] + wo512, wv[ph] + wo512, wo[ph] + wo512,
        wl_qkv, wl_qkv + (size_t)512 * 512, wl_qkv + (size_t)1024 * 512, wl_o);
    convt2i_kernel<<<dim3(16, 48, 2), 256, 0, stream>>>(
        w1[ph] + wo1536, w3[ph] + wo1536, wl_13, 512, 1536);
    convt_kernel<<<dim3(48, 16), 256, 0, stream>>>(w2[ph] + wo1536, wl_2, 1536, 512);
    const float* anl = an[ph] + li * 512;
    const float* fnl = fn[ph] + li * 512;

    for (int c = 0; c < NCHUNK; c++) {
      float* hc = h + (size_t)c * RCHUNK * ND;
      rmsnorm_bf16<<<RCHUNK / 4, 256, 0, stream>>>(hc, anl, xn);
      gemm_bt<0><<<dim3(12, RCHUNK / 128), 256, 0, stream>>>(xn, wl_qkv, g1, (float*)nullptr, 1536, 512, 1536);
      // attention output overlays xn (dead after qkv GEMM)
      if (ph == 0) attn_mfma<32, false><<<dim3(8, RCHUNK / 32), 128, 0, stream>>>(g1, xn);
      else         attn_mfma<64, true ><<<dim3(8, RCHUNK / 64), 256, 0, stream>>>(g1, xn);
      gemm_bt<1><<<dim3(4, RCHUNK / 128), 256, 0, stream>>>(xn, wl_o, (u16*)nullptr, hc, 512, 512, 512);
      rmsnorm_bf16<<<RCHUNK / 4, 256, 0, stream>>>(hc, fnl, xn);
      // fused W1|W3 (column-interleaved) + SwiGLU epilogue -> g1 (M x 1536)
      gemm_bt<3><<<dim3(24, RCHUNK / 128), 256, 0, stream>>>(xn, wl_13, g1, (float*)nullptr, 3072, 512, 1536);
      gemm_bt<1><<<dim3(4, RCHUNK / 128), 256, 0, stream>>>(g1, wl_2, (u16*)nullptr, hc, 512, 1536, 512);
    }

    if (l == 3) {
      // rel->enc handoff: rms_norm + within-batch (p,v)->(v,p) row permute,
      // 8 batches per round through the 33.5 MB bounce (g1 space is dead)
      for (int g = 0; g < 4; g++) {
        float* hg = h + (size_t)g * 8 * 2048 * ND;
        rms_transpose_batch<<<dim3(512, 8), 256, 0, stream>>>(hg, norm_w, bounce);
        copy_f32v4<<<8192, 256, 0, stream>>>((const float4*)bounce, (float4*)hg, 8 * 2048 * ND / 4);
      }
    }
  }

  // head: per-chunk rmsnorm -> 256 complete M-rows of the 1024x96x32768 GEMM
  zero_f32<<<384, 256, 0, stream>>>(z, 1024 * 96);
  for (int c = 0; c < NCHUNK; c++) {
    rmsnorm_bf16<<<RCHUNK / 4, 256, 0, stream>>>(h + (size_t)c * RCHUNK * ND, norm_w, xn);
    head_gemm<<<dim3(RCHUNK / 64 / 64, 32), 256, 0, stream>>>(xn, hw_t, z + (size_t)c * (RCHUNK / 64) * NPRED);
  }
  final_kernel<<<384, 256, 0, stream>>>(z, head_b, meanb, stdevb, (float*)d_out);
}